// Round 4
// baseline (11095.224 us; speedup 1.0000x reference)
//
#include <hip/hip_runtime.h>
#include <cstddef>
#include <cstdint>

// ---------------- problem constants ----------------
constexpr int G      = 8192;
constexpr int NAST   = 32;
constexpr int N0     = G * NAST;    // 262144
constexpr int D_EMB  = 128;
constexpr int C0     = 192;         // 3 * H_IN
constexpr int H_IN   = 64;
constexpr int K0     = 23;          // ceil(0.7*32)
constexpr int N1     = G * K0;      // 188416
constexpr int K1     = 12;          // ceil(0.5*23)
constexpr int ENC    = 128;
constexpr int NSTMT  = 8192;
constexpr int EST    = 32768;
constexpr int HO3    = 384;
constexpr int HOUT   = 128;
constexpr int NSEL   = 4096;

// =====================================================================
// Fused GAT0 v3: per-block = 8 AST graphs (256 rows) x 192 cols, K=128.
// 256 threads, 16x12 register tiles (VALU-bound, LDS-pipe < VALU demand).
// GEMM -> per-graph attention epilogue -> +bias -> tanh -> hA + BN partials.
// =====================================================================
__global__ __launch_bounds__(256, 2) void fused_gat0(
    const float* __restrict__ X, const float* __restrict__ W,
    const int* __restrict__ ast_src,
    const float* __restrict__ asrc_w, const float* __restrict__ adst_w,
    const float* __restrict__ bias,
    float* __restrict__ out, float* __restrict__ psum, float* __restrict__ psq)
{
    __shared__ float smem[7360];       // 29440 B
    float* As = smem;                  // [16][260] k-major, stride 260
    float* Bs = smem + 4160;           // [16][200] k-major, stride 200
    int tid = threadIdx.x;
    int b = blockIdx.x;
    int row0 = b * 256;
    int tm = tid >> 4;                 // 0..15
    int tn = tid & 15;                 // 0..15
    // thread rows: 64*j + tm*4 + u  (j=0..3, u=0..3) ; cols: tn*12 + v

    float acc[16][12] = {};

    for (int kt = 0; kt < 128; kt += 16) {
        // stage A: 256 rows x 16 k. thread = row; 16 floats = one 64B line.
        {
            const float* ap = X + (size_t)(row0 + tid) * 128 + kt;
            float4 x0 = *(const float4*)(ap + 0);
            float4 x1 = *(const float4*)(ap + 4);
            float4 x2 = *(const float4*)(ap + 8);
            float4 x3 = *(const float4*)(ap + 12);
            float xv[16] = {x0.x,x0.y,x0.z,x0.w, x1.x,x1.y,x1.z,x1.w,
                            x2.x,x2.y,x2.z,x2.w, x3.x,x3.y,x3.z,x3.w};
            #pragma unroll
            for (int k = 0; k < 16; ++k) As[k * 260 + tid] = xv[k];
        }
        // stage B: 16 k x 192 n. 768 float4s over 256 threads.
        #pragma unroll
        for (int q = 0; q < 3; ++q) {
            int i = tid + 256 * q;
            int k = i / 48, c4 = (i % 48) * 4;
            *(float4*)&Bs[k * 200 + c4] = *(const float4*)(W + (size_t)(kt + k) * 192 + c4);
        }
        __syncthreads();
        #pragma unroll
        for (int kk = 0; kk < 16; ++kk) {
            const float* arow = &As[kk * 260 + tm * 4];
            float4 a0 = *(const float4*)(arow + 0);
            float4 a1 = *(const float4*)(arow + 64);
            float4 a2 = *(const float4*)(arow + 128);
            float4 a3 = *(const float4*)(arow + 192);
            const float* brow = &Bs[kk * 200 + tn * 12];
            float4 b0 = *(const float4*)(brow + 0);
            float4 b1 = *(const float4*)(brow + 4);
            float4 b2 = *(const float4*)(brow + 8);
            float a_[16] = {a0.x,a0.y,a0.z,a0.w, a1.x,a1.y,a1.z,a1.w,
                            a2.x,a2.y,a2.z,a2.w, a3.x,a3.y,a3.z,a3.w};
            float b_[12] = {b0.x,b0.y,b0.z,b0.w, b1.x,b1.y,b1.z,b1.w,
                            b2.x,b2.y,b2.z,b2.w};
            #pragma unroll
            for (int i = 0; i < 16; ++i)
                #pragma unroll
                for (int v = 0; v < 12; ++v)
                    acc[i][v] += a_[i] * b_[v];
        }
        __syncthreads();
    }

    // ---- phase 2: per-graph attention epilogue (8 graphs sequential) ----
    float* Cs  = smem;                 // [32][196]
    float* as_ = smem + 6272;          // [32][3]
    float* ad_ = as_ + 96;
    float* aS  = ad_ + 96;
    float* aP  = aS + 96;
    int*  parl = (int*)(aP + 96);      // [256] local parent ids, all 8 graphs

    if (tid < 248) {
        int gg = tid / 31, j = tid % 31 + 1;
        int g = b * 8 + gg;
        parl[gg * 32 + j] = ast_src[(size_t)g * 31 + j - 1] - g * 32;
    }
    if (tid < 8) parl[tid * 32] = -1;

    float s = 0.f, s2 = 0.f;
    float bj = (tid < 192) ? bias[tid] : 0.f;

    for (int gg = 0; gg < 8; ++gg) {
        int jg = gg >> 1, half = gg & 1;
        __syncthreads();  // prev graph's Cs reads done
        if ((tm >> 3) == half) {
            int lr0 = (tm - 8 * half) * 4;
            #pragma unroll
            for (int u = 0; u < 4; ++u) {
                float* crow = &Cs[(lr0 + u) * 196 + tn * 12];
                *(float4*)(crow + 0) = *(float4*)&acc[jg * 4 + u][0];
                *(float4*)(crow + 4) = *(float4*)&acc[jg * 4 + u][4];
                *(float4*)(crow + 8) = *(float4*)&acc[jg * 4 + u][8];
            }
        }
        __syncthreads();
        if (tid < 192) {
            int r = tid / 6, q6 = tid % 6, hh = q6 >> 1, sd = q6 & 1;
            const float* w = (sd ? adst_w : asrc_w) + hh * 64;
            const float* crow = &Cs[r * 196 + hh * 64];
            float d = 0.f;
            for (int c = 0; c < 64; ++c) d += crow[c] * w[c];
            (sd ? ad_ : as_)[r * 3 + hh] = d;
        }
        __syncthreads();
        if (tid < 96) {
            int r = tid / 3, hh = tid % 3, p = parl[gg * 32 + r];
            if (p < 0) { aS[r * 3 + hh] = 1.f; aP[r * 3 + hh] = 0.f; }
            else {
                float ls = as_[r * 3 + hh] + ad_[r * 3 + hh]; ls = ls > 0 ? ls : 0.2f * ls;
                float lp = as_[p * 3 + hh] + ad_[r * 3 + hh]; lp = lp > 0 ? lp : 0.2f * lp;
                float m = fmaxf(ls, lp);
                float es = expf(ls - m), ep = expf(lp - m);
                float inv = 1.f / (es + ep);
                aS[r * 3 + hh] = es * inv; aP[r * 3 + hh] = ep * inv;
            }
        }
        __syncthreads();
        if (tid < 192) {
            int j = tid, hh = j >> 6;
            float* outg = out + (size_t)(row0 + 32 * gg) * 192 + j;
            for (int r = 0; r < 32; ++r) {
                int p = parl[gg * 32 + r];
                float v = aS[r * 3 + hh] * Cs[r * 196 + j];
                if (p >= 0) v += aP[r * 3 + hh] * Cs[p * 196 + j];
                v = tanhf(v + bj);
                outg[(size_t)r * 192] = v;
                s += v; s2 += v * v;
            }
        }
    }
    if (tid < 192) {
        psum[(size_t)b * 192 + tid] = s;
        psq [(size_t)b * 192 + tid] = s2;
    }
}

// =====================================================================
// BN finalize: column j of [nb][C] partials -> ga/be + folded gw/bw.
// =====================================================================
__global__ __launch_bounds__(256) void bn_finalize(
    const float* __restrict__ psum, const float* __restrict__ psq, int nb, int C, float R,
    const float* __restrict__ gamma, const float* __restrict__ beta,
    const float* __restrict__ w,
    float* __restrict__ ga, float* __restrict__ be,
    float* __restrict__ gw, float* __restrict__ bw)
{
    int j = blockIdx.x, t = threadIdx.x;
    float s = 0.f, s2 = 0.f;
    for (int i = t; i < nb; i += 256) {
        s  += psum[(size_t)i * C + j];
        s2 += psq [(size_t)i * C + j];
    }
    __shared__ float r1[4], r2[4];
    for (int o = 32; o > 0; o >>= 1) { s += __shfl_down(s, o, 64); s2 += __shfl_down(s2, o, 64); }
    if ((t & 63) == 0) { r1[t >> 6] = s; r2[t >> 6] = s2; }
    __syncthreads();
    if (t == 0) {
        float S = r1[0] + r1[1] + r1[2] + r1[3];
        float S2 = r2[0] + r2[1] + r2[2] + r2[3];
        float mu = S / R, var = S2 / R - mu * mu;
        float inv = 1.f / sqrtf(var + 1e-5f);
        float gaj = gamma[j] * inv, bej = beta[j] - mu * gaj;
        ga[j] = gaj; be[j] = bej; gw[j] = gaj * w[j]; bw[j] = bej * w[j];
    }
}

// =====================================================================
// Score + TopK(32->23) + parent remap. Reads raw hA once.
// =====================================================================
__global__ __launch_bounds__(256) void score_topk0(
    const float* __restrict__ hA, const int* __restrict__ ast_src,
    const float* __restrict__ gw, const float* __restrict__ bw,
    const float* __restrict__ w,
    int* __restrict__ oldrow, float* __restrict__ gate23, int* __restrict__ parloc)
{
    __shared__ float swv[192];
    __shared__ float sc[32];
    __shared__ int nid[32];
    __shared__ float wparts[4], bparts[4];
    int g = blockIdx.x, t = threadIdx.x;
    if (t < 192) swv[t] = gw[t];
    float ws = (t < 192) ? w[t] * w[t] : 0.f;
    float bs = (t < 192) ? bw[t] : 0.f;
    for (int o = 32; o > 0; o >>= 1) { ws += __shfl_down(ws, o, 64); bs += __shfl_down(bs, o, 64); }
    if ((t & 63) == 0) { wparts[t >> 6] = ws; bparts[t >> 6] = bs; }
    __syncthreads();
    float invn = 1.f / sqrtf(wparts[0] + wparts[1] + wparts[2] + wparts[3]);
    float sb = bparts[0] + bparts[1] + bparts[2] + bparts[3];

    int r = t >> 3, j0 = (t & 7) * 24;
    const float4* row4 = (const float4*)(hA + ((size_t)g * 32 + r) * 192 + j0);
    const float4* sw4 = (const float4*)(swv + j0);
    float s = 0.f;
    #pragma unroll
    for (int u = 0; u < 6; ++u) {
        float4 a = row4[u], bv = sw4[u];
        s += a.x * bv.x + a.y * bv.y + a.z * bv.z + a.w * bv.w;
    }
    for (int o = 4; o > 0; o >>= 1) s += __shfl_down(s, o, 8);
    if ((t & 7) == 0) sc[r] = (s + sb) * invn;
    __syncthreads();
    if (t < 32) {
        float v = sc[t]; int rank = 0;
        for (int j = 0; j < 32; ++j) rank += (sc[j] > v) || (sc[j] == v && j < t);
        nid[t] = (rank < 23) ? rank : -1;
    }
    __syncthreads();
    if (t < 32 && nid[t] >= 0) {
        int rank = nid[t];
        oldrow[g * 23 + rank] = g * 32 + t;
        gate23[g * 23 + rank] = tanhf(sc[t]);
        int pl = -1;
        if (t > 0) {
            int p = ast_src[(size_t)g * 31 + t - 1] - g * 32;
            pl = nid[p];
        }
        parloc[g * 23 + rank] = pl;
    }
}

// =====================================================================
// Gather-GEMM: hB[N1,64] = relu((hA[old]*ga+be)*gate) @ gat1_W[192,64]
// =====================================================================
__global__ __launch_bounds__(256) void gemm_gather(
    const float* __restrict__ A, const float* __restrict__ B, float* __restrict__ C,
    const int* __restrict__ rowmap, const float* __restrict__ gate,
    const float* __restrict__ ga, const float* __restrict__ be)
{
    __shared__ float As[16 * 68];
    __shared__ float Bs[16 * 68];
    __shared__ float gas[192], bes[192];
    int tid = threadIdx.x, bm = blockIdx.x;
    if (tid < 192) { gas[tid] = ga[tid]; bes[tid] = be[tid]; }
    int arow = tid >> 2, aks = (tid & 3) * 4;
    int brow = tid >> 4, bns = (tid & 15) * 4;
    int tm = tid >> 4, tn = tid & 15;
    float acc[4][4] = {};
    int grow = bm * 64 + arow;
    int old = rowmap[grow];
    float gt = gate[grow];
    const float* ap = A + (size_t)old * 192;
    __syncthreads();
    for (int kt = 0; kt < 192; kt += 16) {
        float4 av = *(const float4*)(ap + kt + aks);
        int kb = kt + aks;
        av.x = fmaxf((av.x * gas[kb + 0] + bes[kb + 0]) * gt, 0.f);
        av.y = fmaxf((av.y * gas[kb + 1] + bes[kb + 1]) * gt, 0.f);
        av.z = fmaxf((av.z * gas[kb + 2] + bes[kb + 2]) * gt, 0.f);
        av.w = fmaxf((av.w * gas[kb + 3] + bes[kb + 3]) * gt, 0.f);
        As[(aks + 0) * 68 + arow] = av.x;
        As[(aks + 1) * 68 + arow] = av.y;
        As[(aks + 2) * 68 + arow] = av.z;
        As[(aks + 3) * 68 + arow] = av.w;
        *(float4*)&Bs[brow * 68 + bns] = *(const float4*)(B + (size_t)(kt + brow) * 64 + bns);
        __syncthreads();
        #pragma unroll
        for (int kk = 0; kk < 16; ++kk) {
            float4 a4 = *(const float4*)&As[kk * 68 + (tm << 2)];
            float4 b4 = *(const float4*)&Bs[kk * 68 + (tn << 2)];
            float a_[4] = {a4.x, a4.y, a4.z, a4.w};
            float b_[4] = {b4.x, b4.y, b4.z, b4.w};
            #pragma unroll
            for (int i = 0; i < 4; ++i)
                #pragma unroll
                for (int j = 0; j < 4; ++j)
                    acc[i][j] += a_[i] * b_[j];
        }
        __syncthreads();
    }
    #pragma unroll
    for (int i = 0; i < 4; ++i) {
        int rr = bm * 64 + (tm << 2) + i;
        float4 o = {acc[i][0], acc[i][1], acc[i][2], acc[i][3]};
        *(float4*)(C + (size_t)rr * 64 + (tn << 2)) = o;
    }
}

// =====================================================================
// GAT1 attention (in place on hB) + tanh + BN1 partials. 64 threads.
// =====================================================================
__global__ __launch_bounds__(64) void gat1_att_bn(
    float* __restrict__ h, const int* __restrict__ parloc,
    const float* __restrict__ aw_s, const float* __restrict__ aw_d,
    const float* __restrict__ bias,
    float* __restrict__ psum, float* __restrict__ psq)
{
    __shared__ float hs[23 * 65];
    __shared__ float as_[23], ad_[23], aS[23], aP[23];
    __shared__ int parl[23];
    int g = blockIdx.x, t = threadIdx.x;
    float* base = h + (size_t)g * 23 * 64;
    for (int r = 0; r < 23; ++r) hs[r * 65 + t] = base[r * 64 + t];
    if (t < 23) parl[t] = parloc[g * 23 + t];
    __syncthreads();
    if (t < 46) {
        int r = t >> 1, sd = t & 1;
        const float* w = sd ? aw_d : aw_s;
        const float* row = &hs[r * 65];
        float s = 0.f;
        for (int c = 0; c < 64; ++c) s += row[c] * w[c];
        (sd ? ad_ : as_)[r] = s;
    }
    __syncthreads();
    if (t < 23) {
        int p = parl[t];
        if (p < 0) { aS[t] = 1.f; aP[t] = 0.f; }
        else {
            float ls = as_[t] + ad_[t]; ls = ls > 0 ? ls : 0.2f * ls;
            float lp = as_[p] + ad_[t]; lp = lp > 0 ? lp : 0.2f * lp;
            float m = fmaxf(ls, lp);
            float es = expf(ls - m), ep = expf(lp - m);
            float inv = 1.f / (es + ep);
            aS[t] = es * inv; aP[t] = ep * inv;
        }
    }
    __syncthreads();
    float bj = bias[t], s = 0.f, s2 = 0.f;
    for (int r = 0; r < 23; ++r) {
        int p = parl[r];
        float v = aS[r] * hs[r * 65 + t];
        if (p >= 0) v += aP[r] * hs[p * 65 + t];
        v = tanhf(v + bj);
        base[r * 64 + t] = v;
        s += v; s2 += v * v;
    }
    psum[(size_t)g * 64 + t] = s;
    psq [(size_t)g * 64 + t] = s2;
}

// =====================================================================
// Score1 + TopK(23->12) + gated-BN maxpool + relu + encoder MLP -> xenc
// =====================================================================
__global__ __launch_bounds__(128) void pool1_mlp(
    const float* __restrict__ h,
    const float* __restrict__ gw, const float* __restrict__ bw,
    const float* __restrict__ w,
    const float* __restrict__ ga, const float* __restrict__ be,
    const float* __restrict__ w1, const float* __restrict__ b1,
    const float* __restrict__ w2, const float* __restrict__ b2,
    float* __restrict__ xenc)
{
    __shared__ float hs[23 * 65];
    __shared__ float sc[23];
    __shared__ int keep[23];
    __shared__ float feat[64], t1[64];
    __shared__ float consts[2];
    int g = blockIdx.x, t = threadIdx.x;
    const float* base = h + (size_t)g * 23 * 64;
    {
        int c = t & 63;
        for (int r = t >> 6; r < 23; r += 2) hs[r * 65 + c] = base[r * 64 + c];
    }
    if (t < 64) {
        float ws = w[t] * w[t], bs = bw[t];
        for (int o = 32; o > 0; o >>= 1) { ws += __shfl_down(ws, o, 64); bs += __shfl_down(bs, o, 64); }
        if (t == 0) { consts[0] = 1.f / sqrtf(ws); consts[1] = bs; }
    }
    __syncthreads();
    if (t < 23) {
        const float* row = &hs[t * 65];
        float s = 0.f;
        for (int c = 0; c < 64; ++c) s += row[c] * gw[c];
        sc[t] = (s + consts[1]) * consts[0];
    }
    __syncthreads();
    if (t < 23) {
        float v = sc[t]; int rank = 0;
        for (int j = 0; j < 23; ++j) rank += (sc[j] > v) || (sc[j] == v && j < t);
        keep[t] = rank < 12;
    }
    __syncthreads();
    if (t < 23) sc[t] = tanhf(sc[t]);
    __syncthreads();
    if (t < 64) {
        float m = -1e30f, gac = ga[t], bec = be[t];
        for (int r = 0; r < 23; ++r)
            if (keep[r]) m = fmaxf(m, (hs[r * 65 + t] * gac + bec) * sc[r]);
        feat[t] = fmaxf(m, 0.f);
    }
    __syncthreads();
    if (t < 64) {
        float acc = b1[t];
        for (int c = 0; c < 64; ++c) acc += feat[c] * w1[c * 64 + t];
        t1[t] = fmaxf(acc, 0.f);
    }
    __syncthreads();
    float acc = b2[t];
    for (int j = 0; j < 64; ++j) acc += t1[j] * w2[j * 128 + t];
    xenc[(size_t)g * 128 + t] = acc;
}

// =====================================================================
// Generic tiled GEMM (stage B)
// =====================================================================
__global__ __launch_bounds__(256) void gemm_nn(
    const float* __restrict__ A, const float* __restrict__ B, float* __restrict__ C,
    int M, int N, int K)
{
    __shared__ float As[16 * 68];
    __shared__ float Bs[16 * 68];
    int tid = threadIdx.x;
    int bm = blockIdx.x, bn = blockIdx.y;
    int arow = tid >> 2, aks = (tid & 3) * 4;
    int brow = tid >> 4, bns = (tid & 15) * 4;
    int tm = tid >> 4, tn = tid & 15;
    float acc[4][4] = {};
    const float* ap = A + (size_t)(bm * 64 + arow) * K;
    for (int kt = 0; kt < K; kt += 16) {
        float4 av = *(const float4*)(ap + kt + aks);
        As[(aks + 0) * 68 + arow] = av.x;
        As[(aks + 1) * 68 + arow] = av.y;
        As[(aks + 2) * 68 + arow] = av.z;
        As[(aks + 3) * 68 + arow] = av.w;
        *(float4*)&Bs[brow * 68 + bns] = *(const float4*)(B + (size_t)(kt + brow) * N + bn * 64 + bns);
        __syncthreads();
        #pragma unroll
        for (int kk = 0; kk < 16; ++kk) {
            float4 a4 = *(const float4*)&As[kk * 68 + (tm << 2)];
            float4 b4 = *(const float4*)&Bs[kk * 68 + (tn << 2)];
            float a_[4] = {a4.x, a4.y, a4.z, a4.w};
            float b_[4] = {b4.x, b4.y, b4.z, b4.w};
            #pragma unroll
            for (int i = 0; i < 4; ++i)
                #pragma unroll
                for (int j = 0; j < 4; ++j)
                    acc[i][j] += a_[i] * b_[j];
        }
        __syncthreads();
    }
    #pragma unroll
    for (int i = 0; i < 4; ++i) {
        int r = bm * 64 + (tm << 2) + i;
        float4 o = {acc[i][0], acc[i][1], acc[i][2], acc[i][3]};
        *(float4*)(C + (size_t)r * N + bn * 64 + (tn << 2)) = o;
    }
}

// ---------------- BatchNorm (stage B) ----------------
__global__ void bn_stats(const float* __restrict__ X, int R,
                         float* __restrict__ sum, float* __restrict__ sumsq)
{
    int t = threadIdx.x;
    int C = blockDim.x;
    float s = 0.f, s2 = 0.f;
    for (int r = blockIdx.x; r < R; r += gridDim.x) {
        float v = X[(size_t)r * C + t];
        s += v; s2 += v * v;
    }
    atomicAdd(&sum[t], s);
    atomicAdd(&sumsq[t], s2);
}

__global__ void bn_apply(float* __restrict__ X, int R,
                         const float* __restrict__ sum, const float* __restrict__ sumsq,
                         const float* __restrict__ gam, const float* __restrict__ bet)
{
    int t = threadIdx.x;
    int C = blockDim.x;
    float invR = 1.f / (float)R;
    float mu = sum[t] * invR;
    float var = sumsq[t] * invR - mu * mu;
    float inv = 1.f / sqrtf(var + 1e-5f);
    float ga = gam[t] * inv;
    float be = bet[t] - mu * ga;
    for (int r = blockIdx.x; r < R; r += gridDim.x) {
        size_t idx = (size_t)r * C + t;
        X[idx] = X[idx] * ga + be;
    }
}

// ---------------- RGAT qi/kj precompute (3 heads) ----------------
__global__ __launch_bounds__(256) void rgat_qk3(
    const float* __restrict__ h0, const float* __restrict__ h1,
    const float* __restrict__ q, const float* __restrict__ k,
    float* __restrict__ qi, float* __restrict__ kj)
{
    int n = blockIdx.x, t = threadIdx.x;
    float p[12] = {};
    for (int d = t; d < HO3; d += 256) {
        float v0 = h0[(size_t)n * HO3 + d], v1 = h1[(size_t)n * HO3 + d];
        #pragma unroll
        for (int hh = 0; hh < 3; ++hh) {
            float qw = q[d * 3 + hh], kw = k[d * 3 + hh];
            p[hh]     += v0 * qw;  p[3 + hh] += v0 * kw;
            p[6 + hh] += v1 * qw;  p[9 + hh] += v1 * kw;
        }
    }
    __shared__ float red[4][12];
    #pragma unroll
    for (int i = 0; i < 12; ++i) {
        float x = p[i];
        for (int o = 32; o > 0; o >>= 1) x += __shfl_down(x, o, 64);
        if ((t & 63) == 0) red[t >> 6][i] = x;
    }
    __syncthreads();
    if (t < 12) {
        float s = red[0][t] + red[1][t] + red[2][t] + red[3][t];
        int rel = t / 6, rem = t % 6, isk = rem / 3, hh = rem % 3;
        float* dst = isk ? kj : qi;
        dst[((size_t)rel * NSTMT + n) * 3 + hh] = s;
    }
}

__global__ void edge_logits3(const int* __restrict__ src, const int* __restrict__ dst,
                             const int* __restrict__ et,
                             const float* __restrict__ qi, const float* __restrict__ kj,
                             float* __restrict__ logits)
{
    int e = blockIdx.x * 256 + threadIdx.x;
    if (e >= EST) return;
    int r = et[e], s = src[e], d = dst[e];
    #pragma unroll
    for (int hh = 0; hh < 3; ++hh) {
        float x = qi[((size_t)r * NSTMT + d) * 3 + hh] + kj[((size_t)r * NSTMT + s) * 3 + hh];
        logits[e * 3 + hh] = x > 0 ? x : 0.2f * x;
    }
}

// ---------------- CSR build ----------------
__global__ void count_deg(const int* __restrict__ dst, int* __restrict__ deg)
{
    int e = blockIdx.x * 256 + threadIdx.x;
    if (e < EST) atomicAdd(&deg[dst[e]], 1);
}

__global__ void scan_deg(const int* __restrict__ deg, int* __restrict__ offa)
{
    __shared__ int ts[1024];
    int t = threadIdx.x;
    int base = t * 8;
    int loc[8]; int s = 0;
    #pragma unroll
    for (int i = 0; i < 8; ++i) { loc[i] = s; s += deg[base + i]; }
    ts[t] = s;
    __syncthreads();
    for (int o = 1; o < 1024; o <<= 1) {
        int v = (t >= o) ? ts[t - o] : 0;
        __syncthreads();
        ts[t] += v;
        __syncthreads();
    }
    int prev = (t == 0) ? 0 : ts[t - 1];
    #pragma unroll
    for (int i = 0; i < 8; ++i) offa[base + i] = prev + loc[i];
    if (t == 1023) offa[8192] = ts[1023];
}

__global__ void scatter_csr(const int* __restrict__ dst, const int* __restrict__ offa,
                            int* __restrict__ cnt, int* __restrict__ csr)
{
    int e = blockIdx.x * 256 + threadIdx.x;
    if (e < EST) {
        int d = dst[e];
        int pos = offa[d] + atomicAdd(&cnt[d], 1);
        csr[pos] = e;
    }
}

// ---------------- RGAT0 aggregate ----------------
__global__ __launch_bounds__(256) void rgat_agg3(
    const float* __restrict__ h0, const float* __restrict__ h1,
    const int* __restrict__ offa, const int* __restrict__ csr,
    const int* __restrict__ src, const int* __restrict__ et,
    const float* __restrict__ logits, const float* __restrict__ bias,
    float* __restrict__ out)
{
    int n = blockIdx.x, t = threadIdx.x;
    int o0 = offa[n], deg = offa[n + 1] - o0;
    __shared__ float m[3], sden[3];
    __shared__ float al[64][3];
    __shared__ int esrc[64], erel[64];
    if (t < 3) {
        float mm = -1e30f;
        for (int i = 0; i < deg; ++i) mm = fmaxf(mm, logits[csr[o0 + i] * 3 + t]);
        float ss = 0.f;
        for (int i = 0; i < deg; ++i) ss += expf(logits[csr[o0 + i] * 3 + t] - mm);
        m[t] = mm; sden[t] = fmaxf(ss, 1e-16f);
    }
    __syncthreads();
    float acc0 = 0.f, acc1 = 0.f;
    for (int c0 = 0; c0 < deg; c0 += 64) {
        int cn = min(64, deg - c0);
        if (t < cn) { int e = csr[o0 + c0 + t]; esrc[t] = src[e]; erel[t] = et[e]; }
        if (t < cn * 3) {
            int ee = t / 3, hh = t % 3;
            int e = csr[o0 + c0 + ee];
            al[ee][hh] = expf(logits[e * 3 + hh] - m[hh]) / sden[hh];
        }
        __syncthreads();
        for (int i = 0; i < cn; ++i) {
            const float* hb = (erel[i] ? h1 : h0) + (size_t)esrc[i] * HO3;
            acc0 += al[i][t >> 7] * hb[t];
            if (t < 128) acc1 += al[i][(t + 256) >> 7] * hb[t + 256];
        }
        __syncthreads();
    }
    out[(size_t)n * HO3 + t] = tanhf(acc0 + bias[t]);
    if (t < 128) out[(size_t)n * HO3 + t + 256] = tanhf(acc1 + bias[t + 256]);
}

// ---------------- RGAT1 qi/kj ----------------
__global__ __launch_bounds__(128) void rgat_qk1(
    const float* __restrict__ h0, const float* __restrict__ h1,
    const float* __restrict__ q, const float* __restrict__ k,
    float* __restrict__ qi, float* __restrict__ kj)
{
    int n = blockIdx.x, t = threadIdx.x;
    float v0 = h0[(size_t)n * 128 + t], v1 = h1[(size_t)n * 128 + t];
    float p0 = v0 * q[t], p1 = v0 * k[t], p2 = v1 * q[t], p3 = v1 * k[t];
    __shared__ float red[2][4];
    for (int o = 32; o > 0; o >>= 1) {
        p0 += __shfl_down(p0, o, 64); p1 += __shfl_down(p1, o, 64);
        p2 += __shfl_down(p2, o, 64); p3 += __shfl_down(p3, o, 64);
    }
    if ((t & 63) == 0) { int w = t >> 6; red[w][0] = p0; red[w][1] = p1; red[w][2] = p2; red[w][3] = p3; }
    __syncthreads();
    if (t < 4) {
        float s = red[0][t] + red[1][t];
        if (t == 0) qi[n] = s;
        else if (t == 1) kj[n] = s;
        else if (t == 2) qi[NSTMT + n] = s;
        else kj[NSTMT + n] = s;
    }
}

__global__ void edge_logits1(const int* __restrict__ src, const int* __restrict__ dst,
                             const int* __restrict__ et,
                             const float* __restrict__ qi, const float* __restrict__ kj,
                             float* __restrict__ logits)
{
    int e = blockIdx.x * 256 + threadIdx.x;
    if (e >= EST) return;
    int r = et[e], s = src[e], d = dst[e];
    float x = qi[(size_t)r * NSTMT + d] + kj[(size_t)r * NSTMT + s];
    logits[e] = x > 0 ? x : 0.2f * x;
}

// ---------------- RGAT1 aggregate ----------------
__global__ __launch_bounds__(128) void rgat_agg1(
    const float* __restrict__ h0, const float* __restrict__ h1,
    const int* __restrict__ offa, const int* __restrict__ csr,
    const int* __restrict__ src, const int* __restrict__ et,
    const float* __restrict__ logits, const float* __restrict__ bias,
    float* __restrict__ out)
{
    int n = blockIdx.x, t = threadIdx.x;
    int o0 = offa[n], deg = offa[n + 1] - o0;
    __shared__ float m1, s1;
    __shared__ float al[64];
    __shared__ int esrc[64], erel[64];
    if (t == 0) {
        float mm = -1e30f;
        for (int i = 0; i < deg; ++i) mm = fmaxf(mm, logits[csr[o0 + i]]);
        float ss = 0.f;
        for (int i = 0; i < deg; ++i) ss += expf(logits[csr[o0 + i]] - mm);
        m1 = mm; s1 = fmaxf(ss, 1e-16f);
    }
    __syncthreads();
    float acc = 0.f;
    for (int c0 = 0; c0 < deg; c0 += 64) {
        int cn = min(64, deg - c0);
        if (t < cn) {
            int e = csr[o0 + c0 + t];
            esrc[t] = src[e]; erel[t] = et[e];
            al[t] = expf(logits[e] - m1) / s1;
        }
        __syncthreads();
        for (int i = 0; i < cn; ++i)
            acc += al[i] * ((erel[i] ? h1 : h0)[(size_t)esrc[i] * 128 + t]);
        __syncthreads();
    }
    out[(size_t)n * 128 + t] = tanhf(acc + bias[t]);
}

// ---------------- classifier ----------------
__global__ __launch_bounds__(128) void classifier(
    const float* __restrict__ x, const int* __restrict__ sel,
    const float* __restrict__ w1, const float* __restrict__ b1,
    const float* __restrict__ w2, const float* __restrict__ b2,
    float* __restrict__ out)
{
    __shared__ float row[128];
    __shared__ float t1[128];
    __shared__ float red[2];
    int b = blockIdx.x, t = threadIdx.x;
    int n = sel[b];
    row[t] = x[(size_t)n * 128 + t];
    __syncthreads();
    float acc = b1[t];
    for (int k = 0; k < 128; ++k) acc += row[k] * w1[k * 128 + t];
    t1[t] = fmaxf(acc, 0.f);
    __syncthreads();
    float p = t1[t] * w2[t];
    for (int o = 32; o > 0; o >>= 1) p += __shfl_down(p, o, 64);
    if ((t & 63) == 0) red[t >> 6] = p;
    __syncthreads();
    if (t == 0) {
        float z = red[0] + red[1] + b2[0];
        out[b] = 1.f / (1.f + expf(-z));
    }
}

// ---------------- workspace layout (bytes) ----------------
constexpr size_t OFF_HA     = 0;                       // 201326592
constexpr size_t OFF_BN0    = 201326592;               // 4*768
constexpr size_t OFF_BN1    = OFF_BN0 + 3072;          // 4*256
constexpr size_t OFF_OLDROW = OFF_BN1 + 1024;
constexpr size_t OFF_GATE   = OFF_OLDROW + 753664;
constexpr size_t OFF_PARLOC = OFF_GATE + 753664;
constexpr size_t OFF_HB     = OFF_PARLOC + 753664;     // 48234496 (psum0/psq0 alias)
constexpr size_t OFF_XENC   = OFF_HB + 48234496;       // 4194304 (psum1/psq1 alias)
constexpr size_t OFF_BNSUM  = OFF_XENC + 4194304;
constexpr size_t OFF_BNSQ   = OFF_BNSUM + 1536;
constexpr size_t WS_NEEDED  = OFF_BNSQ + 1536;
// stage-B aliases inside hA (dead after gemm_gather):
constexpr size_t OFF_H0R  = 0;
constexpr size_t OFF_H1R  = 12582912;
constexpr size_t OFF_OUT0 = 25165824;
constexpr size_t OFF_G0   = 37748736;
constexpr size_t OFF_G1   = 41943040;
constexpr size_t OFF_OUT1 = 46137344;
constexpr size_t OFF_QI3  = 50331648;
constexpr size_t OFF_KJ3  = 50528256;
constexpr size_t OFF_LG3  = 50724864;
constexpr size_t OFF_QI1  = 51118080;
constexpr size_t OFF_KJ1  = 51183616;
constexpr size_t OFF_LG1  = 51249152;
constexpr size_t OFF_DEG  = 51380224;
constexpr size_t OFF_OFFA = 51412992;
constexpr size_t OFF_CNT  = 51446016;
constexpr size_t OFF_CSR  = 51478784;

extern "C" void kernel_launch(void* const* d_in, const int* in_sizes, int n_in,
                              void* d_out, int out_size, void* d_ws, size_t ws_size,
                              hipStream_t stream)
{
    if (n_in < 41 || ws_size < WS_NEEDED) return;

    const float* ast_x    = (const float*)d_in[0];
    const int*   ast_src  = (const int*)d_in[1];
    const int*   stmt_src = (const int*)d_in[3];
    const int*   stmt_dst = (const int*)d_in[4];
    const int*   stmt_et  = (const int*)d_in[5];
    const int*   sel      = (const int*)d_in[6];
    const float* gat0_W    = (const float*)d_in[7];
    const float* gat0_asrc = (const float*)d_in[8];
    const float* gat0_adst = (const float*)d_in[9];
    const float* gat0_b    = (const float*)d_in[10];
    const float* bn0_g     = (const float*)d_in[11];
    const float* bn0_b     = (const float*)d_in[12];
    const float* pool0_w   = (const float*)d_in[13];
    const float* gat1_W    = (const float*)d_in[14];
    const float* gat1_asrc = (const float*)d_in[15];
    const float* gat1_adst = (const float*)d_in[16];
    const float* gat1_b    = (const float*)d_in[17];
    const float* bn1_g     = (const float*)d_in[18];
    const float* bn1_b     = (const float*)d_in[19];
    const float* pool1_w   = (const float*)d_in[20];
    const float* enc_w1    = (const float*)d_in[21];
    const float* enc_b1    = (const float*)d_in[22];
    const float* enc_w2    = (const float*)d_in[23];
    const float* enc_b2    = (const float*)d_in[24];
    const float* rgat0_W   = (const float*)d_in[25];
    const float* rgat0_q   = (const float*)d_in[26];
    const float* rgat0_k   = (const float*)d_in[27];
    const float* rgat0_b   = (const float*)d_in[28];
    const float* bnc0_g    = (const float*)d_in[29];
    const float* bnc0_b    = (const float*)d_in[30];
    const float* rgat1_W   = (const float*)d_in[31];
    const float* rgat1_q   = (const float*)d_in[32];
    const float* rgat1_k   = (const float*)d_in[33];
    const float* rgat1_b   = (const float*)d_in[34];
    const float* bnc1_g    = (const float*)d_in[35];
    const float* bnc1_b    = (const float*)d_in[36];
    const float* clf_w1    = (const float*)d_in[37];
    const float* clf_b1    = (const float*)d_in[38];
    const float* clf_w2    = (const float*)d_in[39];
    const float* clf_b2    = (const float*)d_in[40];

    char* ws = (char*)d_ws;
    float* hA     = (float*)(ws + OFF_HA);
    float* ga0    = (float*)(ws + OFF_BN0);
    float* be0    = ga0 + 192;
    float* gw0    = be0 + 192;
    float* bw0    = gw0 + 192;
    float* ga1    = (float*)(ws + OFF_BN1);
    float* be1    = ga1 + 64;
    float* gw1    = be1 + 64;
    float* bw1    = gw1 + 64;
    int*   oldrow = (int*)(ws + OFF_OLDROW);
    float* gate23 = (float*)(ws + OFF_GATE);
    int*   parloc = (int*)(ws + OFF_PARLOC);
    float* hB     = (float*)(ws + OFF_HB);
    float* psum0  = (float*)(ws + OFF_HB);           // [1024][192] alias
    float* psq0   = psum0 + 192 * 1024;
    float* xenc   = (float*)(ws + OFF_XENC);
    float* psum1  = (float*)(ws + OFF_XENC);         // [8192][64] alias
    float* psq1   = psum1 + 64 * 8192;
    float* bnsum  = (float*)(ws + OFF_BNSUM);
    float* bnsq   = (float*)(ws + OFF_BNSQ);

    float* h0r  = (float*)(ws + OFF_H0R);
    float* h1r  = (float*)(ws + OFF_H1R);
    float* out0 = (float*)(ws + OFF_OUT0);
    float* g0   = (float*)(ws + OFF_G0);
    float* g1   = (float*)(ws + OFF_G1);
    float* out1 = (float*)(ws + OFF_OUT1);
    float* qi3  = (float*)(ws + OFF_QI3);
    float* kj3  = (float*)(ws + OFF_KJ3);
    float* lg3  = (float*)(ws + OFF_LG3);
    float* qi1  = (float*)(ws + OFF_QI1);
    float* kj1  = (float*)(ws + OFF_KJ1);
    float* lg1  = (float*)(ws + OFF_LG1);
    int*   deg  = (int*)(ws + OFF_DEG);
    int*   offa = (int*)(ws + OFF_OFFA);
    int*   cnt  = (int*)(ws + OFF_CNT);
    int*   csr  = (int*)(ws + OFF_CSR);

    // ---- Stage A ----
    fused_gat0<<<1024, 256, 0, stream>>>(ast_x, gat0_W, ast_src, gat0_asrc, gat0_adst,
                                         gat0_b, hA, psum0, psq0);
    bn_finalize<<<192, 256, 0, stream>>>(psum0, psq0, 1024, 192, (float)N0,
                                         bn0_g, bn0_b, pool0_w, ga0, be0, gw0, bw0);
    score_topk0<<<G, 256, 0, stream>>>(hA, ast_src, gw0, bw0, pool0_w,
                                       oldrow, gate23, parloc);
    gemm_gather<<<N1 / 64, 256, 0, stream>>>(hA, gat1_W, hB, oldrow, gate23, ga0, be0);
    gat1_att_bn<<<G, 64, 0, stream>>>(hB, parloc, gat1_asrc, gat1_adst, gat1_b,
                                      psum1, psq1);
    bn_finalize<<<64, 256, 0, stream>>>(psum1, psq1, 8192, 64, (float)N1,
                                        bn1_g, bn1_b, pool1_w, ga1, be1, gw1, bw1);
    pool1_mlp<<<G, 128, 0, stream>>>(hB, gw1, bw1, pool1_w, ga1, be1,
                                     enc_w1, enc_b1, enc_w2, enc_b2, xenc);

    // ---- Stage B ----
    gemm_nn<<<dim3(NSTMT / 64, HO3 / 64), 256, 0, stream>>>(xenc, rgat0_W, h0r, NSTMT, HO3, ENC);
    gemm_nn<<<dim3(NSTMT / 64, HO3 / 64), 256, 0, stream>>>(xenc, rgat0_W + (size_t)ENC * HO3, h1r, NSTMT, HO3, ENC);
    rgat_qk3<<<NSTMT, 256, 0, stream>>>(h0r, h1r, rgat0_q, rgat0_k, qi3, kj3);
    edge_logits3<<<EST / 256, 256, 0, stream>>>(stmt_src, stmt_dst, stmt_et, qi3, kj3, lg3);
    hipMemsetAsync(deg, 0, 32768, stream);
    hipMemsetAsync(cnt, 0, 32768, stream);
    count_deg<<<EST / 256, 256, 0, stream>>>(stmt_dst, deg);
    scan_deg<<<1, 1024, 0, stream>>>(deg, offa);
    scatter_csr<<<EST / 256, 256, 0, stream>>>(stmt_dst, offa, cnt, csr);
    rgat_agg3<<<NSTMT, 256, 0, stream>>>(h0r, h1r, offa, csr, stmt_src, stmt_et, lg3, rgat0_b, out0);
    hipMemsetAsync(bnsum, 0, 3072, stream);
    bn_stats<<<256, HO3, 0, stream>>>(out0, NSTMT, bnsum, bnsq);
    bn_apply<<<256, HO3, 0, stream>>>(out0, NSTMT, bnsum, bnsq, bnc0_g, bnc0_b);
    gemm_nn<<<dim3(NSTMT / 64, HOUT / 64), 256, 0, stream>>>(out0, rgat1_W, g0, NSTMT, HOUT, HO3);
    gemm_nn<<<dim3(NSTMT / 64, HOUT / 64), 256, 0, stream>>>(out0, rgat1_W + (size_t)HO3 * HOUT, g1, NSTMT, HOUT, HO3);
    rgat_qk1<<<NSTMT, 128, 0, stream>>>(g0, g1, rgat1_q, rgat1_k, qi1, kj1);
    edge_logits1<<<EST / 256, 256, 0, stream>>>(stmt_src, stmt_dst, stmt_et, qi1, kj1, lg1);
    rgat_agg1<<<NSTMT, 128, 0, stream>>>(g0, g1, offa, csr, stmt_src, stmt_et, lg1, rgat1_b, out1);
    hipMemsetAsync(bnsum, 0, 3072, stream);
    bn_stats<<<256, HOUT, 0, stream>>>(out1, NSTMT, bnsum, bnsq);
    bn_apply<<<256, HOUT, 0, stream>>>(out1, NSTMT, bnsum, bnsq, bnc1_g, bnc1_b);
    classifier<<<NSEL, 128, 0, stream>>>(out1, sel, clf_w1, clf_b1, clf_w2, clf_b2, (float*)d_out);
}

// Round 5
// 1276.936 us; speedup vs baseline: 8.6889x; 8.6889x over previous
//
#include <hip/hip_runtime.h>
#include <cstddef>
#include <cstdint>

// ---------------- problem constants ----------------
constexpr int G      = 8192;
constexpr int NAST   = 32;
constexpr int N0     = G * NAST;    // 262144
constexpr int D_EMB  = 128;
constexpr int C0     = 192;         // 3 * H_IN
constexpr int H_IN   = 64;
constexpr int K0     = 23;          // ceil(0.7*32)
constexpr int N1     = G * K0;      // 188416
constexpr int K1     = 12;          // ceil(0.5*23)
constexpr int ENC    = 128;
constexpr int NSTMT  = 8192;
constexpr int EST    = 32768;
constexpr int HO3    = 384;
constexpr int HOUT   = 128;
constexpr int NSEL   = 4096;

// =====================================================================
// Fused GAT0 v3b: per-block = 8 AST graphs (256 rows) x 192 cols, K=128.
// 256 threads, 16x12 register tiles. Epilogue loop FULLY UNROLLED so the
// accumulator array is statically indexed (rule #20: dynamic index ->
// scratch spill, which was round 4's 30x regression).
// =====================================================================
__global__ __launch_bounds__(256, 2) void fused_gat0(
    const float* __restrict__ X, const float* __restrict__ W,
    const int* __restrict__ ast_src,
    const float* __restrict__ asrc_w, const float* __restrict__ adst_w,
    const float* __restrict__ bias,
    float* __restrict__ out, float* __restrict__ psum, float* __restrict__ psq)
{
    __shared__ float smem[7360];       // 29440 B
    float* As = smem;                  // [16][260] k-major, stride 260
    float* Bs = smem + 4160;           // [16][200] k-major, stride 200
    int tid = threadIdx.x;
    int b = blockIdx.x;
    int row0 = b * 256;
    int tm = tid >> 4;                 // 0..15
    int tn = tid & 15;                 // 0..15

    float acc[16][12] = {};

    for (int kt = 0; kt < 128; kt += 16) {
        {
            const float* ap = X + (size_t)(row0 + tid) * 128 + kt;
            float4 x0 = *(const float4*)(ap + 0);
            float4 x1 = *(const float4*)(ap + 4);
            float4 x2 = *(const float4*)(ap + 8);
            float4 x3 = *(const float4*)(ap + 12);
            float xv[16] = {x0.x,x0.y,x0.z,x0.w, x1.x,x1.y,x1.z,x1.w,
                            x2.x,x2.y,x2.z,x2.w, x3.x,x3.y,x3.z,x3.w};
            #pragma unroll
            for (int k = 0; k < 16; ++k) As[k * 260 + tid] = xv[k];
        }
        #pragma unroll
        for (int q = 0; q < 3; ++q) {
            int i = tid + 256 * q;
            int k = i / 48, c4 = (i % 48) * 4;
            *(float4*)&Bs[k * 200 + c4] = *(const float4*)(W + (size_t)(kt + k) * 192 + c4);
        }
        __syncthreads();
        #pragma unroll
        for (int kk = 0; kk < 16; ++kk) {
            const float* arow = &As[kk * 260 + tm * 4];
            float4 a0 = *(const float4*)(arow + 0);
            float4 a1 = *(const float4*)(arow + 64);
            float4 a2 = *(const float4*)(arow + 128);
            float4 a3 = *(const float4*)(arow + 192);
            const float* brow = &Bs[kk * 200 + tn * 12];
            float4 b0 = *(const float4*)(brow + 0);
            float4 b1 = *(const float4*)(brow + 4);
            float4 b2 = *(const float4*)(brow + 8);
            float a_[16] = {a0.x,a0.y,a0.z,a0.w, a1.x,a1.y,a1.z,a1.w,
                            a2.x,a2.y,a2.z,a2.w, a3.x,a3.y,a3.z,a3.w};
            float b_[12] = {b0.x,b0.y,b0.z,b0.w, b1.x,b1.y,b1.z,b1.w,
                            b2.x,b2.y,b2.z,b2.w};
            #pragma unroll
            for (int i = 0; i < 16; ++i)
                #pragma unroll
                for (int v = 0; v < 12; ++v)
                    acc[i][v] += a_[i] * b_[v];
        }
        __syncthreads();
    }

    // ---- phase 2: per-graph attention epilogue (8 graphs, UNROLLED) ----
    float* Cs  = smem;                 // [32][196]
    float* as_ = smem + 6272;          // [32][3]
    float* ad_ = as_ + 96;
    float* aS  = ad_ + 96;
    float* aP  = aS + 96;
    int*  parl = (int*)(aP + 96);      // [256]

    if (tid < 248) {
        int gg = tid / 31, j = tid % 31 + 1;
        int g = b * 8 + gg;
        parl[gg * 32 + j] = ast_src[(size_t)g * 31 + j - 1] - g * 32;
    }
    if (tid < 8) parl[tid * 32] = -1;

    float s = 0.f, s2 = 0.f;
    float bj = (tid < 192) ? bias[tid] : 0.f;

    #pragma unroll
    for (int gg = 0; gg < 8; ++gg) {
        const int jg = gg >> 1, half = gg & 1;
        __syncthreads();  // prev graph's Cs reads done
        if ((tm >> 3) == half) {
            const int lr0 = (tm - 8 * half) * 4;
            #pragma unroll
            for (int u = 0; u < 4; ++u) {
                float* crow = &Cs[(lr0 + u) * 196 + tn * 12];
                *(float4*)(crow + 0) = *(float4*)&acc[jg * 4 + u][0];
                *(float4*)(crow + 4) = *(float4*)&acc[jg * 4 + u][4];
                *(float4*)(crow + 8) = *(float4*)&acc[jg * 4 + u][8];
            }
        }
        __syncthreads();
        if (tid < 192) {
            int r = tid / 6, q6 = tid % 6, hh = q6 >> 1, sd = q6 & 1;
            const float* w = (sd ? adst_w : asrc_w) + hh * 64;
            const float* crow = &Cs[r * 196 + hh * 64];
            float d = 0.f;
            for (int c = 0; c < 64; ++c) d += crow[c] * w[c];
            (sd ? ad_ : as_)[r * 3 + hh] = d;
        }
        __syncthreads();
        if (tid < 96) {
            int r = tid / 3, hh = tid % 3, p = parl[gg * 32 + r];
            if (p < 0) { aS[r * 3 + hh] = 1.f; aP[r * 3 + hh] = 0.f; }
            else {
                float ls = as_[r * 3 + hh] + ad_[r * 3 + hh]; ls = ls > 0 ? ls : 0.2f * ls;
                float lp = as_[p * 3 + hh] + ad_[r * 3 + hh]; lp = lp > 0 ? lp : 0.2f * lp;
                float m = fmaxf(ls, lp);
                float es = expf(ls - m), ep = expf(lp - m);
                float inv = 1.f / (es + ep);
                aS[r * 3 + hh] = es * inv; aP[r * 3 + hh] = ep * inv;
            }
        }
        __syncthreads();
        if (tid < 192) {
            int j = tid, hh = j >> 6;
            float* outg = out + (size_t)(row0 + 32 * gg) * 192 + j;
            for (int r = 0; r < 32; ++r) {
                int p = parl[gg * 32 + r];
                float v = aS[r * 3 + hh] * Cs[r * 196 + j];
                if (p >= 0) v += aP[r * 3 + hh] * Cs[p * 196 + j];
                v = tanhf(v + bj);
                outg[(size_t)r * 192] = v;
                s += v; s2 += v * v;
            }
        }
    }
    if (tid < 192) {
        psum[(size_t)b * 192 + tid] = s;
        psq [(size_t)b * 192 + tid] = s2;
    }
}

// =====================================================================
// BN finalize: column j of [nb][C] partials -> ga/be + folded gw/bw.
// =====================================================================
__global__ __launch_bounds__(256) void bn_finalize(
    const float* __restrict__ psum, const float* __restrict__ psq, int nb, int C, float R,
    const float* __restrict__ gamma, const float* __restrict__ beta,
    const float* __restrict__ w,
    float* __restrict__ ga, float* __restrict__ be,
    float* __restrict__ gw, float* __restrict__ bw)
{
    int j = blockIdx.x, t = threadIdx.x;
    float s = 0.f, s2 = 0.f;
    for (int i = t; i < nb; i += 256) {
        s  += psum[(size_t)i * C + j];
        s2 += psq [(size_t)i * C + j];
    }
    __shared__ float r1[4], r2[4];
    for (int o = 32; o > 0; o >>= 1) { s += __shfl_down(s, o, 64); s2 += __shfl_down(s2, o, 64); }
    if ((t & 63) == 0) { r1[t >> 6] = s; r2[t >> 6] = s2; }
    __syncthreads();
    if (t == 0) {
        float S = r1[0] + r1[1] + r1[2] + r1[3];
        float S2 = r2[0] + r2[1] + r2[2] + r2[3];
        float mu = S / R, var = S2 / R - mu * mu;
        float inv = 1.f / sqrtf(var + 1e-5f);
        float gaj = gamma[j] * inv, bej = beta[j] - mu * gaj;
        ga[j] = gaj; be[j] = bej; gw[j] = gaj * w[j]; bw[j] = bej * w[j];
    }
}

// =====================================================================
// Score + TopK(32->23) + parent remap. Reads raw hA once.
// =====================================================================
__global__ __launch_bounds__(256) void score_topk0(
    const float* __restrict__ hA, const int* __restrict__ ast_src,
    const float* __restrict__ gw, const float* __restrict__ bw,
    const float* __restrict__ w,
    int* __restrict__ oldrow, float* __restrict__ gate23, int* __restrict__ parloc)
{
    __shared__ float swv[192];
    __shared__ float sc[32];
    __shared__ int nid[32];
    __shared__ float wparts[4], bparts[4];
    int g = blockIdx.x, t = threadIdx.x;
    if (t < 192) swv[t] = gw[t];
    float ws = (t < 192) ? w[t] * w[t] : 0.f;
    float bs = (t < 192) ? bw[t] : 0.f;
    for (int o = 32; o > 0; o >>= 1) { ws += __shfl_down(ws, o, 64); bs += __shfl_down(bs, o, 64); }
    if ((t & 63) == 0) { wparts[t >> 6] = ws; bparts[t >> 6] = bs; }
    __syncthreads();
    float invn = 1.f / sqrtf(wparts[0] + wparts[1] + wparts[2] + wparts[3]);
    float sb = bparts[0] + bparts[1] + bparts[2] + bparts[3];

    int r = t >> 3, j0 = (t & 7) * 24;
    const float4* row4 = (const float4*)(hA + ((size_t)g * 32 + r) * 192 + j0);
    const float4* sw4 = (const float4*)(swv + j0);
    float s = 0.f;
    #pragma unroll
    for (int u = 0; u < 6; ++u) {
        float4 a = row4[u], bv = sw4[u];
        s += a.x * bv.x + a.y * bv.y + a.z * bv.z + a.w * bv.w;
    }
    for (int o = 4; o > 0; o >>= 1) s += __shfl_down(s, o, 8);
    if ((t & 7) == 0) sc[r] = (s + sb) * invn;
    __syncthreads();
    if (t < 32) {
        float v = sc[t]; int rank = 0;
        for (int j = 0; j < 32; ++j) rank += (sc[j] > v) || (sc[j] == v && j < t);
        nid[t] = (rank < 23) ? rank : -1;
    }
    __syncthreads();
    if (t < 32 && nid[t] >= 0) {
        int rank = nid[t];
        oldrow[g * 23 + rank] = g * 32 + t;
        gate23[g * 23 + rank] = tanhf(sc[t]);
        int pl = -1;
        if (t > 0) {
            int p = ast_src[(size_t)g * 31 + t - 1] - g * 32;
            pl = nid[p];
        }
        parloc[g * 23 + rank] = pl;
    }
}

// =====================================================================
// Gather-GEMM: hB[N1,64] = relu((hA[old]*ga+be)*gate) @ gat1_W[192,64]
// =====================================================================
__global__ __launch_bounds__(256) void gemm_gather(
    const float* __restrict__ A, const float* __restrict__ B, float* __restrict__ C,
    const int* __restrict__ rowmap, const float* __restrict__ gate,
    const float* __restrict__ ga, const float* __restrict__ be)
{
    __shared__ float As[16 * 68];
    __shared__ float Bs[16 * 68];
    __shared__ float gas[192], bes[192];
    int tid = threadIdx.x, bm = blockIdx.x;
    if (tid < 192) { gas[tid] = ga[tid]; bes[tid] = be[tid]; }
    int arow = tid >> 2, aks = (tid & 3) * 4;
    int brow = tid >> 4, bns = (tid & 15) * 4;
    int tm = tid >> 4, tn = tid & 15;
    float acc[4][4] = {};
    int grow = bm * 64 + arow;
    int old = rowmap[grow];
    float gt = gate[grow];
    const float* ap = A + (size_t)old * 192;
    __syncthreads();
    for (int kt = 0; kt < 192; kt += 16) {
        float4 av = *(const float4*)(ap + kt + aks);
        int kb = kt + aks;
        av.x = fmaxf((av.x * gas[kb + 0] + bes[kb + 0]) * gt, 0.f);
        av.y = fmaxf((av.y * gas[kb + 1] + bes[kb + 1]) * gt, 0.f);
        av.z = fmaxf((av.z * gas[kb + 2] + bes[kb + 2]) * gt, 0.f);
        av.w = fmaxf((av.w * gas[kb + 3] + bes[kb + 3]) * gt, 0.f);
        As[(aks + 0) * 68 + arow] = av.x;
        As[(aks + 1) * 68 + arow] = av.y;
        As[(aks + 2) * 68 + arow] = av.z;
        As[(aks + 3) * 68 + arow] = av.w;
        *(float4*)&Bs[brow * 68 + bns] = *(const float4*)(B + (size_t)(kt + brow) * 64 + bns);
        __syncthreads();
        #pragma unroll
        for (int kk = 0; kk < 16; ++kk) {
            float4 a4 = *(const float4*)&As[kk * 68 + (tm << 2)];
            float4 b4 = *(const float4*)&Bs[kk * 68 + (tn << 2)];
            float a_[4] = {a4.x, a4.y, a4.z, a4.w};
            float b_[4] = {b4.x, b4.y, b4.z, b4.w};
            #pragma unroll
            for (int i = 0; i < 4; ++i)
                #pragma unroll
                for (int j = 0; j < 4; ++j)
                    acc[i][j] += a_[i] * b_[j];
        }
        __syncthreads();
    }
    #pragma unroll
    for (int i = 0; i < 4; ++i) {
        int rr = bm * 64 + (tm << 2) + i;
        float4 o = {acc[i][0], acc[i][1], acc[i][2], acc[i][3]};
        *(float4*)(C + (size_t)rr * 64 + (tn << 2)) = o;
    }
}

// =====================================================================
// GAT1 attention (in place on hB) + tanh + BN1 partials. 64 threads.
// =====================================================================
__global__ __launch_bounds__(64) void gat1_att_bn(
    float* __restrict__ h, const int* __restrict__ parloc,
    const float* __restrict__ aw_s, const float* __restrict__ aw_d,
    const float* __restrict__ bias,
    float* __restrict__ psum, float* __restrict__ psq)
{
    __shared__ float hs[23 * 65];
    __shared__ float as_[23], ad_[23], aS[23], aP[23];
    __shared__ int parl[23];
    int g = blockIdx.x, t = threadIdx.x;
    float* base = h + (size_t)g * 23 * 64;
    for (int r = 0; r < 23; ++r) hs[r * 65 + t] = base[r * 64 + t];
    if (t < 23) parl[t] = parloc[g * 23 + t];
    __syncthreads();
    if (t < 46) {
        int r = t >> 1, sd = t & 1;
        const float* w = sd ? aw_d : aw_s;
        const float* row = &hs[r * 65];
        float s = 0.f;
        for (int c = 0; c < 64; ++c) s += row[c] * w[c];
        (sd ? ad_ : as_)[r] = s;
    }
    __syncthreads();
    if (t < 23) {
        int p = parl[t];
        if (p < 0) { aS[t] = 1.f; aP[t] = 0.f; }
        else {
            float ls = as_[t] + ad_[t]; ls = ls > 0 ? ls : 0.2f * ls;
            float lp = as_[p] + ad_[t]; lp = lp > 0 ? lp : 0.2f * lp;
            float m = fmaxf(ls, lp);
            float es = expf(ls - m), ep = expf(lp - m);
            float inv = 1.f / (es + ep);
            aS[t] = es * inv; aP[t] = ep * inv;
        }
    }
    __syncthreads();
    float bj = bias[t], s = 0.f, s2 = 0.f;
    for (int r = 0; r < 23; ++r) {
        int p = parl[r];
        float v = aS[r] * hs[r * 65 + t];
        if (p >= 0) v += aP[r] * hs[p * 65 + t];
        v = tanhf(v + bj);
        base[r * 64 + t] = v;
        s += v; s2 += v * v;
    }
    psum[(size_t)g * 64 + t] = s;
    psq [(size_t)g * 64 + t] = s2;
}

// =====================================================================
// Score1 + TopK(23->12) + gated-BN maxpool + relu + encoder MLP -> xenc
// =====================================================================
__global__ __launch_bounds__(128) void pool1_mlp(
    const float* __restrict__ h,
    const float* __restrict__ gw, const float* __restrict__ bw,
    const float* __restrict__ w,
    const float* __restrict__ ga, const float* __restrict__ be,
    const float* __restrict__ w1, const float* __restrict__ b1,
    const float* __restrict__ w2, const float* __restrict__ b2,
    float* __restrict__ xenc)
{
    __shared__ float hs[23 * 65];
    __shared__ float sc[23];
    __shared__ int keep[23];
    __shared__ float feat[64], t1[64];
    __shared__ float consts[2];
    int g = blockIdx.x, t = threadIdx.x;
    const float* base = h + (size_t)g * 23 * 64;
    {
        int c = t & 63;
        for (int r = t >> 6; r < 23; r += 2) hs[r * 65 + c] = base[r * 64 + c];
    }
    if (t < 64) {
        float ws = w[t] * w[t], bs = bw[t];
        for (int o = 32; o > 0; o >>= 1) { ws += __shfl_down(ws, o, 64); bs += __shfl_down(bs, o, 64); }
        if (t == 0) { consts[0] = 1.f / sqrtf(ws); consts[1] = bs; }
    }
    __syncthreads();
    if (t < 23) {
        const float* row = &hs[t * 65];
        float s = 0.f;
        for (int c = 0; c < 64; ++c) s += row[c] * gw[c];
        sc[t] = (s + consts[1]) * consts[0];
    }
    __syncthreads();
    if (t < 23) {
        float v = sc[t]; int rank = 0;
        for (int j = 0; j < 23; ++j) rank += (sc[j] > v) || (sc[j] == v && j < t);
        keep[t] = rank < 12;
    }
    __syncthreads();
    if (t < 23) sc[t] = tanhf(sc[t]);
    __syncthreads();
    if (t < 64) {
        float m = -1e30f, gac = ga[t], bec = be[t];
        for (int r = 0; r < 23; ++r)
            if (keep[r]) m = fmaxf(m, (hs[r * 65 + t] * gac + bec) * sc[r]);
        feat[t] = fmaxf(m, 0.f);
    }
    __syncthreads();
    if (t < 64) {
        float acc = b1[t];
        for (int c = 0; c < 64; ++c) acc += feat[c] * w1[c * 64 + t];
        t1[t] = fmaxf(acc, 0.f);
    }
    __syncthreads();
    float acc = b2[t];
    for (int j = 0; j < 64; ++j) acc += t1[j] * w2[j * 128 + t];
    xenc[(size_t)g * 128 + t] = acc;
}

// =====================================================================
// Generic tiled GEMM (stage B)
// =====================================================================
__global__ __launch_bounds__(256) void gemm_nn(
    const float* __restrict__ A, const float* __restrict__ B, float* __restrict__ C,
    int M, int N, int K)
{
    __shared__ float As[16 * 68];
    __shared__ float Bs[16 * 68];
    int tid = threadIdx.x;
    int bm = blockIdx.x, bn = blockIdx.y;
    int arow = tid >> 2, aks = (tid & 3) * 4;
    int brow = tid >> 4, bns = (tid & 15) * 4;
    int tm = tid >> 4, tn = tid & 15;
    float acc[4][4] = {};
    const float* ap = A + (size_t)(bm * 64 + arow) * K;
    for (int kt = 0; kt < K; kt += 16) {
        float4 av = *(const float4*)(ap + kt + aks);
        As[(aks + 0) * 68 + arow] = av.x;
        As[(aks + 1) * 68 + arow] = av.y;
        As[(aks + 2) * 68 + arow] = av.z;
        As[(aks + 3) * 68 + arow] = av.w;
        *(float4*)&Bs[brow * 68 + bns] = *(const float4*)(B + (size_t)(kt + brow) * N + bn * 64 + bns);
        __syncthreads();
        #pragma unroll
        for (int kk = 0; kk < 16; ++kk) {
            float4 a4 = *(const float4*)&As[kk * 68 + (tm << 2)];
            float4 b4 = *(const float4*)&Bs[kk * 68 + (tn << 2)];
            float a_[4] = {a4.x, a4.y, a4.z, a4.w};
            float b_[4] = {b4.x, b4.y, b4.z, b4.w};
            #pragma unroll
            for (int i = 0; i < 4; ++i)
                #pragma unroll
                for (int j = 0; j < 4; ++j)
                    acc[i][j] += a_[i] * b_[j];
        }
        __syncthreads();
    }
    #pragma unroll
    for (int i = 0; i < 4; ++i) {
        int r = bm * 64 + (tm << 2) + i;
        float4 o = {acc[i][0], acc[i][1], acc[i][2], acc[i][3]};
        *(float4*)(C + (size_t)r * N + bn * 64 + (tn << 2)) = o;
    }
}

// ---------------- BatchNorm (stage B) ----------------
__global__ void bn_stats(const float* __restrict__ X, int R,
                         float* __restrict__ sum, float* __restrict__ sumsq)
{
    int t = threadIdx.x;
    int C = blockDim.x;
    float s = 0.f, s2 = 0.f;
    for (int r = blockIdx.x; r < R; r += gridDim.x) {
        float v = X[(size_t)r * C + t];
        s += v; s2 += v * v;
    }
    atomicAdd(&sum[t], s);
    atomicAdd(&sumsq[t], s2);
}

__global__ void bn_apply(float* __restrict__ X, int R,
                         const float* __restrict__ sum, const float* __restrict__ sumsq,
                         const float* __restrict__ gam, const float* __restrict__ bet)
{
    int t = threadIdx.x;
    int C = blockDim.x;
    float invR = 1.f / (float)R;
    float mu = sum[t] * invR;
    float var = sumsq[t] * invR - mu * mu;
    float inv = 1.f / sqrtf(var + 1e-5f);
    float ga = gam[t] * inv;
    float be = bet[t] - mu * ga;
    for (int r = blockIdx.x; r < R; r += gridDim.x) {
        size_t idx = (size_t)r * C + t;
        X[idx] = X[idx] * ga + be;
    }
}

// ---------------- RGAT qi/kj precompute (3 heads) ----------------
__global__ __launch_bounds__(256) void rgat_qk3(
    const float* __restrict__ h0, const float* __restrict__ h1,
    const float* __restrict__ q, const float* __restrict__ k,
    float* __restrict__ qi, float* __restrict__ kj)
{
    int n = blockIdx.x, t = threadIdx.x;
    float p[12] = {};
    for (int d = t; d < HO3; d += 256) {
        float v0 = h0[(size_t)n * HO3 + d], v1 = h1[(size_t)n * HO3 + d];
        #pragma unroll
        for (int hh = 0; hh < 3; ++hh) {
            float qw = q[d * 3 + hh], kw = k[d * 3 + hh];
            p[hh]     += v0 * qw;  p[3 + hh] += v0 * kw;
            p[6 + hh] += v1 * qw;  p[9 + hh] += v1 * kw;
        }
    }
    __shared__ float red[4][12];
    #pragma unroll
    for (int i = 0; i < 12; ++i) {
        float x = p[i];
        for (int o = 32; o > 0; o >>= 1) x += __shfl_down(x, o, 64);
        if ((t & 63) == 0) red[t >> 6][i] = x;
    }
    __syncthreads();
    if (t < 12) {
        float s = red[0][t] + red[1][t] + red[2][t] + red[3][t];
        int rel = t / 6, rem = t % 6, isk = rem / 3, hh = rem % 3;
        float* dst = isk ? kj : qi;
        dst[((size_t)rel * NSTMT + n) * 3 + hh] = s;
    }
}

__global__ void edge_logits3(const int* __restrict__ src, const int* __restrict__ dst,
                             const int* __restrict__ et,
                             const float* __restrict__ qi, const float* __restrict__ kj,
                             float* __restrict__ logits)
{
    int e = blockIdx.x * 256 + threadIdx.x;
    if (e >= EST) return;
    int r = et[e], s = src[e], d = dst[e];
    #pragma unroll
    for (int hh = 0; hh < 3; ++hh) {
        float x = qi[((size_t)r * NSTMT + d) * 3 + hh] + kj[((size_t)r * NSTMT + s) * 3 + hh];
        logits[e * 3 + hh] = x > 0 ? x : 0.2f * x;
    }
}

// ---------------- CSR build ----------------
__global__ void count_deg(const int* __restrict__ dst, int* __restrict__ deg)
{
    int e = blockIdx.x * 256 + threadIdx.x;
    if (e < EST) atomicAdd(&deg[dst[e]], 1);
}

__global__ void scan_deg(const int* __restrict__ deg, int* __restrict__ offa)
{
    __shared__ int ts[1024];
    int t = threadIdx.x;
    int base = t * 8;
    int loc[8]; int s = 0;
    #pragma unroll
    for (int i = 0; i < 8; ++i) { loc[i] = s; s += deg[base + i]; }
    ts[t] = s;
    __syncthreads();
    for (int o = 1; o < 1024; o <<= 1) {
        int v = (t >= o) ? ts[t - o] : 0;
        __syncthreads();
        ts[t] += v;
        __syncthreads();
    }
    int prev = (t == 0) ? 0 : ts[t - 1];
    #pragma unroll
    for (int i = 0; i < 8; ++i) offa[base + i] = prev + loc[i];
    if (t == 1023) offa[8192] = ts[1023];
}

__global__ void scatter_csr(const int* __restrict__ dst, const int* __restrict__ offa,
                            int* __restrict__ cnt, int* __restrict__ csr)
{
    int e = blockIdx.x * 256 + threadIdx.x;
    if (e < EST) {
        int d = dst[e];
        int pos = offa[d] + atomicAdd(&cnt[d], 1);
        csr[pos] = e;
    }
}

// ---------------- RGAT0 aggregate ----------------
__global__ __launch_bounds__(256) void rgat_agg3(
    const float* __restrict__ h0, const float* __restrict__ h1,
    const int* __restrict__ offa, const int* __restrict__ csr,
    const int* __restrict__ src, const int* __restrict__ et,
    const float* __restrict__ logits, const float* __restrict__ bias,
    float* __restrict__ out)
{
    int n = blockIdx.x, t = threadIdx.x;
    int o0 = offa[n], deg = offa[n + 1] - o0;
    __shared__ float m[3], sden[3];
    __shared__ float al[64][3];
    __shared__ int esrc[64], erel[64];
    if (t < 3) {
        float mm = -1e30f;
        for (int i = 0; i < deg; ++i) mm = fmaxf(mm, logits[csr[o0 + i] * 3 + t]);
        float ss = 0.f;
        for (int i = 0; i < deg; ++i) ss += expf(logits[csr[o0 + i] * 3 + t] - mm);
        m[t] = mm; sden[t] = fmaxf(ss, 1e-16f);
    }
    __syncthreads();
    float acc0 = 0.f, acc1 = 0.f;
    for (int c0 = 0; c0 < deg; c0 += 64) {
        int cn = min(64, deg - c0);
        if (t < cn) { int e = csr[o0 + c0 + t]; esrc[t] = src[e]; erel[t] = et[e]; }
        if (t < cn * 3) {
            int ee = t / 3, hh = t % 3;
            int e = csr[o0 + c0 + ee];
            al[ee][hh] = expf(logits[e * 3 + hh] - m[hh]) / sden[hh];
        }
        __syncthreads();
        for (int i = 0; i < cn; ++i) {
            const float* hb = (erel[i] ? h1 : h0) + (size_t)esrc[i] * HO3;
            acc0 += al[i][t >> 7] * hb[t];
            if (t < 128) acc1 += al[i][(t + 256) >> 7] * hb[t + 256];
        }
        __syncthreads();
    }
    out[(size_t)n * HO3 + t] = tanhf(acc0 + bias[t]);
    if (t < 128) out[(size_t)n * HO3 + t + 256] = tanhf(acc1 + bias[t + 256]);
}

// ---------------- RGAT1 qi/kj ----------------
__global__ __launch_bounds__(128) void rgat_qk1(
    const float* __restrict__ h0, const float* __restrict__ h1,
    const float* __restrict__ q, const float* __restrict__ k,
    float* __restrict__ qi, float* __restrict__ kj)
{
    int n = blockIdx.x, t = threadIdx.x;
    float v0 = h0[(size_t)n * 128 + t], v1 = h1[(size_t)n * 128 + t];
    float p0 = v0 * q[t], p1 = v0 * k[t], p2 = v1 * q[t], p3 = v1 * k[t];
    __shared__ float red[2][4];
    for (int o = 32; o > 0; o >>= 1) {
        p0 += __shfl_down(p0, o, 64); p1 += __shfl_down(p1, o, 64);
        p2 += __shfl_down(p2, o, 64); p3 += __shfl_down(p3, o, 64);
    }
    if ((t & 63) == 0) { int w = t >> 6; red[w][0] = p0; red[w][1] = p1; red[w][2] = p2; red[w][3] = p3; }
    __syncthreads();
    if (t < 4) {
        float s = red[0][t] + red[1][t];
        if (t == 0) qi[n] = s;
        else if (t == 1) kj[n] = s;
        else if (t == 2) qi[NSTMT + n] = s;
        else kj[NSTMT + n] = s;
    }
}

__global__ void edge_logits1(const int* __restrict__ src, const int* __restrict__ dst,
                             const int* __restrict__ et,
                             const float* __restrict__ qi, const float* __restrict__ kj,
                             float* __restrict__ logits)
{
    int e = blockIdx.x * 256 + threadIdx.x;
    if (e >= EST) return;
    int r = et[e], s = src[e], d = dst[e];
    float x = qi[(size_t)r * NSTMT + d] + kj[(size_t)r * NSTMT + s];
    logits[e] = x > 0 ? x : 0.2f * x;
}

// ---------------- RGAT1 aggregate ----------------
__global__ __launch_bounds__(128) void rgat_agg1(
    const float* __restrict__ h0, const float* __restrict__ h1,
    const int* __restrict__ offa, const int* __restrict__ csr,
    const int* __restrict__ src, const int* __restrict__ et,
    const float* __restrict__ logits, const float* __restrict__ bias,
    float* __restrict__ out)
{
    int n = blockIdx.x, t = threadIdx.x;
    int o0 = offa[n], deg = offa[n + 1] - o0;
    __shared__ float m1, s1;
    __shared__ float al[64];
    __shared__ int esrc[64], erel[64];
    if (t == 0) {
        float mm = -1e30f;
        for (int i = 0; i < deg; ++i) mm = fmaxf(mm, logits[csr[o0 + i]]);
        float ss = 0.f;
        for (int i = 0; i < deg; ++i) ss += expf(logits[csr[o0 + i]] - mm);
        m1 = mm; s1 = fmaxf(ss, 1e-16f);
    }
    __syncthreads();
    float acc = 0.f;
    for (int c0 = 0; c0 < deg; c0 += 64) {
        int cn = min(64, deg - c0);
        if (t < cn) {
            int e = csr[o0 + c0 + t];
            esrc[t] = src[e]; erel[t] = et[e];
            al[t] = expf(logits[e] - m1) / s1;
        }
        __syncthreads();
        for (int i = 0; i < cn; ++i)
            acc += al[i] * ((erel[i] ? h1 : h0)[(size_t)esrc[i] * 128 + t]);
        __syncthreads();
    }
    out[(size_t)n * 128 + t] = tanhf(acc + bias[t]);
}

// ---------------- classifier ----------------
__global__ __launch_bounds__(128) void classifier(
    const float* __restrict__ x, const int* __restrict__ sel,
    const float* __restrict__ w1, const float* __restrict__ b1,
    const float* __restrict__ w2, const float* __restrict__ b2,
    float* __restrict__ out)
{
    __shared__ float row[128];
    __shared__ float t1[128];
    __shared__ float red[2];
    int b = blockIdx.x, t = threadIdx.x;
    int n = sel[b];
    row[t] = x[(size_t)n * 128 + t];
    __syncthreads();
    float acc = b1[t];
    for (int k = 0; k < 128; ++k) acc += row[k] * w1[k * 128 + t];
    t1[t] = fmaxf(acc, 0.f);
    __syncthreads();
    float p = t1[t] * w2[t];
    for (int o = 32; o > 0; o >>= 1) p += __shfl_down(p, o, 64);
    if ((t & 63) == 0) red[t >> 6] = p;
    __syncthreads();
    if (t == 0) {
        float z = red[0] + red[1] + b2[0];
        out[b] = 1.f / (1.f + expf(-z));
    }
}

// ---------------- workspace layout (bytes) ----------------
constexpr size_t OFF_HA     = 0;                       // 201326592
constexpr size_t OFF_BN0    = 201326592;               // 4*768
constexpr size_t OFF_BN1    = OFF_BN0 + 3072;          // 4*256
constexpr size_t OFF_OLDROW = OFF_BN1 + 1024;
constexpr size_t OFF_GATE   = OFF_OLDROW + 753664;
constexpr size_t OFF_PARLOC = OFF_GATE + 753664;
constexpr size_t OFF_HB     = OFF_PARLOC + 753664;     // 48234496 (psum0/psq0 alias)
constexpr size_t OFF_XENC   = OFF_HB + 48234496;       // 4194304 (psum1/psq1 alias)
constexpr size_t OFF_BNSUM  = OFF_XENC + 4194304;
constexpr size_t OFF_BNSQ   = OFF_BNSUM + 1536;
constexpr size_t WS_NEEDED  = OFF_BNSQ + 1536;
// stage-B aliases inside hA (dead after gemm_gather):
constexpr size_t OFF_H0R  = 0;
constexpr size_t OFF_H1R  = 12582912;
constexpr size_t OFF_OUT0 = 25165824;
constexpr size_t OFF_G0   = 37748736;
constexpr size_t OFF_G1   = 41943040;
constexpr size_t OFF_OUT1 = 46137344;
constexpr size_t OFF_QI3  = 50331648;
constexpr size_t OFF_KJ3  = 50528256;
constexpr size_t OFF_LG3  = 50724864;
constexpr size_t OFF_QI1  = 51118080;
constexpr size_t OFF_KJ1  = 51183616;
constexpr size_t OFF_LG1  = 51249152;
constexpr size_t OFF_DEG  = 51380224;
constexpr size_t OFF_OFFA = 51412992;
constexpr size_t OFF_CNT  = 51446016;
constexpr size_t OFF_CSR  = 51478784;

extern "C" void kernel_launch(void* const* d_in, const int* in_sizes, int n_in,
                              void* d_out, int out_size, void* d_ws, size_t ws_size,
                              hipStream_t stream)
{
    if (n_in < 41 || ws_size < WS_NEEDED) return;

    const float* ast_x    = (const float*)d_in[0];
    const int*   ast_src  = (const int*)d_in[1];
    const int*   stmt_src = (const int*)d_in[3];
    const int*   stmt_dst = (const int*)d_in[4];
    const int*   stmt_et  = (const int*)d_in[5];
    const int*   sel      = (const int*)d_in[6];
    const float* gat0_W    = (const float*)d_in[7];
    const float* gat0_asrc = (const float*)d_in[8];
    const float* gat0_adst = (const float*)d_in[9];
    const float* gat0_b    = (const float*)d_in[10];
    const float* bn0_g     = (const float*)d_in[11];
    const float* bn0_b     = (const float*)d_in[12];
    const float* pool0_w   = (const float*)d_in[13];
    const float* gat1_W    = (const float*)d_in[14];
    const float* gat1_asrc = (const float*)d_in[15];
    const float* gat1_adst = (const float*)d_in[16];
    const float* gat1_b    = (const float*)d_in[17];
    const float* bn1_g     = (const float*)d_in[18];
    const float* bn1_b     = (const float*)d_in[19];
    const float* pool1_w   = (const float*)d_in[20];
    const float* enc_w1    = (const float*)d_in[21];
    const float* enc_b1    = (const float*)d_in[22];
    const float* enc_w2    = (const float*)d_in[23];
    const float* enc_b2    = (const float*)d_in[24];
    const float* rgat0_W   = (const float*)d_in[25];
    const float* rgat0_q   = (const float*)d_in[26];
    const float* rgat0_k   = (const float*)d_in[27];
    const float* rgat0_b   = (const float*)d_in[28];
    const float* bnc0_g    = (const float*)d_in[29];
    const float* bnc0_b    = (const float*)d_in[30];
    const float* rgat1_W   = (const float*)d_in[31];
    const float* rgat1_q   = (const float*)d_in[32];
    const float* rgat1_k   = (const float*)d_in[33];
    const float* rgat1_b   = (const float*)d_in[34];
    const float* bnc1_g    = (const float*)d_in[35];
    const float* bnc1_b    = (const float*)d_in[36];
    const float* clf_w1    = (const float*)d_in[37];
    const float* clf_b1    = (const float*)d_in[38];
    const float* clf_w2    = (const float*)d_in[39];
    const float* clf_b2    = (const float*)d_in[40];

    char* ws = (char*)d_ws;
    float* hA     = (float*)(ws + OFF_HA);
    float* ga0    = (float*)(ws + OFF_BN0);
    float* be0    = ga0 + 192;
    float* gw0    = be0 + 192;
    float* bw0    = gw0 + 192;
    float* ga1    = (float*)(ws + OFF_BN1);
    float* be1    = ga1 + 64;
    float* gw1    = be1 + 64;
    float* bw1    = gw1 + 64;
    int*   oldrow = (int*)(ws + OFF_OLDROW);
    float* gate23 = (float*)(ws + OFF_GATE);
    int*   parloc = (int*)(ws + OFF_PARLOC);
    float* hB     = (float*)(ws + OFF_HB);
    float* psum0  = (float*)(ws + OFF_HB);           // [1024][192] alias
    float* psq0   = psum0 + 192 * 1024;
    float* xenc   = (float*)(ws + OFF_XENC);
    float* psum1  = (float*)(ws + OFF_XENC);         // [8192][64] alias
    float* psq1   = psum1 + 64 * 8192;
    float* bnsum  = (float*)(ws + OFF_BNSUM);
    float* bnsq   = (float*)(ws + OFF_BNSQ);

    float* h0r  = (float*)(ws + OFF_H0R);
    float* h1r  = (float*)(ws + OFF_H1R);
    float* out0 = (float*)(ws + OFF_OUT0);
    float* g0   = (float*)(ws + OFF_G0);
    float* g1   = (float*)(ws + OFF_G1);
    float* out1 = (float*)(ws + OFF_OUT1);
    float* qi3  = (float*)(ws + OFF_QI3);
    float* kj3  = (float*)(ws + OFF_KJ3);
    float* lg3  = (float*)(ws + OFF_LG3);
    float* qi1  = (float*)(ws + OFF_QI1);
    float* kj1  = (float*)(ws + OFF_KJ1);
    float* lg1  = (float*)(ws + OFF_LG1);
    int*   deg  = (int*)(ws + OFF_DEG);
    int*   offa = (int*)(ws + OFF_OFFA);
    int*   cnt  = (int*)(ws + OFF_CNT);
    int*   csr  = (int*)(ws + OFF_CSR);

    // ---- Stage A ----
    fused_gat0<<<1024, 256, 0, stream>>>(ast_x, gat0_W, ast_src, gat0_asrc, gat0_adst,
                                         gat0_b, hA, psum0, psq0);
    bn_finalize<<<192, 256, 0, stream>>>(psum0, psq0, 1024, 192, (float)N0,
                                         bn0_g, bn0_b, pool0_w, ga0, be0, gw0, bw0);
    score_topk0<<<G, 256, 0, stream>>>(hA, ast_src, gw0, bw0, pool0_w,
                                       oldrow, gate23, parloc);
    gemm_gather<<<N1 / 64, 256, 0, stream>>>(hA, gat1_W, hB, oldrow, gate23, ga0, be0);
    gat1_att_bn<<<G, 64, 0, stream>>>(hB, parloc, gat1_asrc, gat1_adst, gat1_b,
                                      psum1, psq1);
    bn_finalize<<<64, 256, 0, stream>>>(psum1, psq1, 8192, 64, (float)N1,
                                        bn1_g, bn1_b, pool1_w, ga1, be1, gw1, bw1);
    pool1_mlp<<<G, 128, 0, stream>>>(hB, gw1, bw1, pool1_w, ga1, be1,
                                     enc_w1, enc_b1, enc_w2, enc_b2, xenc);

    // ---- Stage B ----
    gemm_nn<<<dim3(NSTMT / 64, HO3 / 64), 256, 0, stream>>>(xenc, rgat0_W, h0r, NSTMT, HO3, ENC);
    gemm_nn<<<dim3(NSTMT / 64, HO3 / 64), 256, 0, stream>>>(xenc, rgat0_W + (size_t)ENC * HO3, h1r, NSTMT, HO3, ENC);
    rgat_qk3<<<NSTMT, 256, 0, stream>>>(h0r, h1r, rgat0_q, rgat0_k, qi3, kj3);
    edge_logits3<<<EST / 256, 256, 0, stream>>>(stmt_src, stmt_dst, stmt_et, qi3, kj3, lg3);
    hipMemsetAsync(deg, 0, 32768, stream);
    hipMemsetAsync(cnt, 0, 32768, stream);
    count_deg<<<EST / 256, 256, 0, stream>>>(stmt_dst, deg);
    scan_deg<<<1, 1024, 0, stream>>>(deg, offa);
    scatter_csr<<<EST / 256, 256, 0, stream>>>(stmt_dst, offa, cnt, csr);
    rgat_agg3<<<NSTMT, 256, 0, stream>>>(h0r, h1r, offa, csr, stmt_src, stmt_et, lg3, rgat0_b, out0);
    hipMemsetAsync(bnsum, 0, 3072, stream);
    bn_stats<<<256, HO3, 0, stream>>>(out0, NSTMT, bnsum, bnsq);
    bn_apply<<<256, HO3, 0, stream>>>(out0, NSTMT, bnsum, bnsq, bnc0_g, bnc0_b);
    gemm_nn<<<dim3(NSTMT / 64, HOUT / 64), 256, 0, stream>>>(out0, rgat1_W, g0, NSTMT, HOUT, HO3);
    gemm_nn<<<dim3(NSTMT / 64, HOUT / 64), 256, 0, stream>>>(out0, rgat1_W + (size_t)HO3 * HOUT, g1, NSTMT, HOUT, HO3);
    rgat_qk1<<<NSTMT, 128, 0, stream>>>(g0, g1, rgat1_q, rgat1_k, qi1, kj1);
    edge_logits1<<<EST / 256, 256, 0, stream>>>(stmt_src, stmt_dst, stmt_et, qi1, kj1, lg1);
    rgat_agg1<<<NSTMT, 128, 0, stream>>>(g0, g1, offa, csr, stmt_src, stmt_et, lg1, rgat1_b, out1);
    hipMemsetAsync(bnsum, 0, 3072, stream);
    bn_stats<<<256, HOUT, 0, stream>>>(out1, NSTMT, bnsum, bnsq);
    bn_apply<<<256, HOUT, 0, stream>>>(out1, NSTMT, bnsum, bnsq, bnc1_g, bnc1_b);
    classifier<<<NSEL, 128, 0, stream>>>(out1, sel, clf_w1, clf_b1, clf_w2, clf_b2, (float*)d_out);
}

// Round 9
// 1049.812 us; speedup vs baseline: 10.5688x; 1.2163x over previous
//
#include <hip/hip_runtime.h>
#include <cstddef>
#include <cstdint>

// ---------------- problem constants ----------------
constexpr int G      = 8192;
constexpr int NAST   = 32;
constexpr int N0     = G * NAST;    // 262144
constexpr int D_EMB  = 128;
constexpr int C0     = 192;         // 3 * H_IN
constexpr int H_IN   = 64;
constexpr int K0     = 23;          // ceil(0.7*32)
constexpr int N1     = G * K0;      // 188416
constexpr int K1     = 12;          // ceil(0.5*23)
constexpr int ENC    = 128;
constexpr int NSTMT  = 8192;
constexpr int EST    = 32768;
constexpr int HO3    = 384;
constexpr int HOUT   = 128;
constexpr int NSEL   = 4096;

// =====================================================================
// Fused GAT0 v4: per-block = 4 AST graphs (128 rows) x 192 cols, K=128.
// 256 threads, 8x12 register tiles (96 acc; balance model -> ~80% VALU,
// fits any VGPR budget without spill). Plain __launch_bounds__(256):
// the (256,2) variant empirically capped VGPR at 128 and spilled.
// All acc indexing is compile-time static (rule #20).
// =====================================================================
__global__ __launch_bounds__(256) void fused_gat0(
    const float* __restrict__ X, const float* __restrict__ W,
    const int* __restrict__ ast_src,
    const float* __restrict__ asrc_w, const float* __restrict__ adst_w,
    const float* __restrict__ bias,
    float* __restrict__ out, float* __restrict__ psum, float* __restrict__ psq)
{
    __shared__ float smem[6784];       // 27136 B (phase1: 5312, phase2: 6784)
    float* As = smem;                  // [16][132] k-major
    float* Bs = smem + 2112;           // [16][200] k-major
    int tid = threadIdx.x;
    int b = blockIdx.x;
    int row0 = b * 128;
    int tm = tid >> 4;                 // 0..15 : rows tm*8 .. tm*8+7
    int tn = tid & 15;                 // 0..15 : cols tn*12 .. +11

    float acc[8][12] = {};

    int arow = tid >> 1;               // 0..127
    int akof = (tid & 1) * 8;          // 0 or 8

    for (int kt = 0; kt < 128; kt += 16) {
        // stage A: 128 rows x 16 k (2 threads/row, 8 k each)
        {
            const float* ap = X + (size_t)(row0 + arow) * 128 + kt + akof;
            float4 x0 = *(const float4*)(ap + 0);
            float4 x1 = *(const float4*)(ap + 4);
            float xv[8] = {x0.x, x0.y, x0.z, x0.w, x1.x, x1.y, x1.z, x1.w};
            #pragma unroll
            for (int j = 0; j < 8; ++j) As[(akof + j) * 132 + arow] = xv[j];
        }
        // stage B: 16 k x 192 n (3 float4 / thread)
        #pragma unroll
        for (int q = 0; q < 3; ++q) {
            int i = tid + 256 * q;
            int k = i / 48, c4 = (i % 48) * 4;
            *(float4*)&Bs[k * 200 + c4] = *(const float4*)(W + (size_t)(kt + k) * 192 + c4);
        }
        __syncthreads();
        #pragma unroll
        for (int kk = 0; kk < 16; ++kk) {
            const float* arp = &As[kk * 132 + tm * 8];
            float4 a0 = *(const float4*)(arp + 0);
            float4 a1 = *(const float4*)(arp + 4);
            const float* brp = &Bs[kk * 200 + tn * 12];
            float4 b0 = *(const float4*)(brp + 0);
            float4 b1 = *(const float4*)(brp + 4);
            float4 b2 = *(const float4*)(brp + 8);
            float a_[8]  = {a0.x,a0.y,a0.z,a0.w, a1.x,a1.y,a1.z,a1.w};
            float b_[12] = {b0.x,b0.y,b0.z,b0.w, b1.x,b1.y,b1.z,b1.w,
                            b2.x,b2.y,b2.z,b2.w};
            #pragma unroll
            for (int i = 0; i < 8; ++i)
                #pragma unroll
                for (int v = 0; v < 12; ++v)
                    acc[i][v] += a_[i] * b_[v];
        }
        __syncthreads();
    }

    // ---- phase 2: per-graph attention epilogue (4 graphs) ----
    float* Cs  = smem;                 // [32][196]
    float* as_ = smem + 6272;          // [32][3]
    float* ad_ = as_ + 96;
    float* aS  = ad_ + 96;
    float* aP  = aS + 96;
    int*  parl = (int*)(smem + 6656);  // [128]

    if (tid < 124) {
        int gg = tid / 31, j = tid % 31 + 1;
        int g = b * 4 + gg;
        parl[gg * 32 + j] = ast_src[(size_t)g * 31 + j - 1] - g * 32;
    }
    if (tid < 4) parl[tid * 32] = -1;

    float s = 0.f, s2 = 0.f;
    float bj = (tid < 192) ? bias[tid] : 0.f;

    #pragma unroll
    for (int gg = 0; gg < 4; ++gg) {
        __syncthreads();  // prev graph's Cs reads (and parl writes at gg=0) done
        if ((tm >> 2) == gg) {
            const int lr0 = (tm & 3) * 8;
            #pragma unroll
            for (int u = 0; u < 8; ++u) {
                float* crow = &Cs[(lr0 + u) * 196 + tn * 12];
                *(float4*)(crow + 0) = *(float4*)&acc[u][0];
                *(float4*)(crow + 4) = *(float4*)&acc[u][4];
                *(float4*)(crow + 8) = *(float4*)&acc[u][8];
            }
        }
        __syncthreads();
        if (tid < 192) {
            int r = tid / 6, q6 = tid % 6, hh = q6 >> 1, sd = q6 & 1;
            const float* w = (sd ? adst_w : asrc_w) + hh * 64;
            const float* crow = &Cs[r * 196 + hh * 64];
            float d = 0.f;
            for (int c = 0; c < 64; ++c) d += crow[c] * w[c];
            (sd ? ad_ : as_)[r * 3 + hh] = d;
        }
        __syncthreads();
        if (tid < 96) {
            int r = tid / 3, hh = tid % 3, p = parl[gg * 32 + r];
            if (p < 0) { aS[r * 3 + hh] = 1.f; aP[r * 3 + hh] = 0.f; }
            else {
                float ls = as_[r * 3 + hh] + ad_[r * 3 + hh]; ls = ls > 0 ? ls : 0.2f * ls;
                float lp = as_[p * 3 + hh] + ad_[r * 3 + hh]; lp = lp > 0 ? lp : 0.2f * lp;
                float m = fmaxf(ls, lp);
                float es = expf(ls - m), ep = expf(lp - m);
                float inv = 1.f / (es + ep);
                aS[r * 3 + hh] = es * inv; aP[r * 3 + hh] = ep * inv;
            }
        }
        __syncthreads();
        if (tid < 192) {
            int j = tid, hh = j >> 6;
            float* outg = out + (size_t)(row0 + 32 * gg) * 192 + j;
            for (int r = 0; r < 32; ++r) {
                int p = parl[gg * 32 + r];
                float v = aS[r * 3 + hh] * Cs[r * 196 + j];
                if (p >= 0) v += aP[r * 3 + hh] * Cs[p * 196 + j];
                v = tanhf(v + bj);
                outg[(size_t)r * 192] = v;
                s += v; s2 += v * v;
            }
        }
    }
    if (tid < 192) {
        psum[(size_t)b * 192 + tid] = s;
        psq [(size_t)b * 192 + tid] = s2;
    }
}

// =====================================================================
// BN finalize: column j of [nb][C] partials -> ga/be + folded gw/bw.
// =====================================================================
__global__ __launch_bounds__(256) void bn_finalize(
    const float* __restrict__ psum, const float* __restrict__ psq, int nb, int C, float R,
    const float* __restrict__ gamma, const float* __restrict__ beta,
    const float* __restrict__ w,
    float* __restrict__ ga, float* __restrict__ be,
    float* __restrict__ gw, float* __restrict__ bw)
{
    int j = blockIdx.x, t = threadIdx.x;
    float s = 0.f, s2 = 0.f;
    for (int i = t; i < nb; i += 256) {
        s  += psum[(size_t)i * C + j];
        s2 += psq [(size_t)i * C + j];
    }
    __shared__ float r1[4], r2[4];
    for (int o = 32; o > 0; o >>= 1) { s += __shfl_down(s, o, 64); s2 += __shfl_down(s2, o, 64); }
    if ((t & 63) == 0) { r1[t >> 6] = s; r2[t >> 6] = s2; }
    __syncthreads();
    if (t == 0) {
        float S = r1[0] + r1[1] + r1[2] + r1[3];
        float S2 = r2[0] + r2[1] + r2[2] + r2[3];
        float mu = S / R, var = S2 / R - mu * mu;
        float inv = 1.f / sqrtf(var + 1e-5f);
        float gaj = gamma[j] * inv, bej = beta[j] - mu * gaj;
        ga[j] = gaj; be[j] = bej; gw[j] = gaj * w[j]; bw[j] = bej * w[j];
    }
}

// =====================================================================
// Score + TopK(32->23) + parent remap. Reads raw hA once.
// =====================================================================
__global__ __launch_bounds__(256) void score_topk0(
    const float* __restrict__ hA, const int* __restrict__ ast_src,
    const float* __restrict__ gw, const float* __restrict__ bw,
    const float* __restrict__ w,
    int* __restrict__ oldrow, float* __restrict__ gate23, int* __restrict__ parloc)
{
    __shared__ float swv[192];
    __shared__ float sc[32];
    __shared__ int nid[32];
    __shared__ float wparts[4], bparts[4];
    int g = blockIdx.x, t = threadIdx.x;
    if (t < 192) swv[t] = gw[t];
    float ws = (t < 192) ? w[t] * w[t] : 0.f;
    float bs = (t < 192) ? bw[t] : 0.f;
    for (int o = 32; o > 0; o >>= 1) { ws += __shfl_down(ws, o, 64); bs += __shfl_down(bs, o, 64); }
    if ((t & 63) == 0) { wparts[t >> 6] = ws; bparts[t >> 6] = bs; }
    __syncthreads();
    float invn = 1.f / sqrtf(wparts[0] + wparts[1] + wparts[2] + wparts[3]);
    float sb = bparts[0] + bparts[1] + bparts[2] + bparts[3];

    int r = t >> 3, j0 = (t & 7) * 24;
    const float4* row4 = (const float4*)(hA + ((size_t)g * 32 + r) * 192 + j0);
    const float4* sw4 = (const float4*)(swv + j0);
    float s = 0.f;
    #pragma unroll
    for (int u = 0; u < 6; ++u) {
        float4 a = row4[u], bv = sw4[u];
        s += a.x * bv.x + a.y * bv.y + a.z * bv.z + a.w * bv.w;
    }
    for (int o = 4; o > 0; o >>= 1) s += __shfl_down(s, o, 8);
    if ((t & 7) == 0) sc[r] = (s + sb) * invn;
    __syncthreads();
    if (t < 32) {
        float v = sc[t]; int rank = 0;
        for (int j = 0; j < 32; ++j) rank += (sc[j] > v) || (sc[j] == v && j < t);
        nid[t] = (rank < 23) ? rank : -1;
    }
    __syncthreads();
    if (t < 32 && nid[t] >= 0) {
        int rank = nid[t];
        oldrow[g * 23 + rank] = g * 32 + t;
        gate23[g * 23 + rank] = tanhf(sc[t]);
        int pl = -1;
        if (t > 0) {
            int p = ast_src[(size_t)g * 31 + t - 1] - g * 32;
            pl = nid[p];
        }
        parloc[g * 23 + rank] = pl;
    }
}

// =====================================================================
// Gather-GEMM: hB[N1,64] = relu((hA[old]*ga+be)*gate) @ gat1_W[192,64]
// =====================================================================
__global__ __launch_bounds__(256) void gemm_gather(
    const float* __restrict__ A, const float* __restrict__ B, float* __restrict__ C,
    const int* __restrict__ rowmap, const float* __restrict__ gate,
    const float* __restrict__ ga, const float* __restrict__ be)
{
    __shared__ float As[16 * 68];
    __shared__ float Bs[16 * 68];
    __shared__ float gas[192], bes[192];
    int tid = threadIdx.x, bm = blockIdx.x;
    if (tid < 192) { gas[tid] = ga[tid]; bes[tid] = be[tid]; }
    int arow = tid >> 2, aks = (tid & 3) * 4;
    int brow = tid >> 4, bns = (tid & 15) * 4;
    int tm = tid >> 4, tn = tid & 15;
    float acc[4][4] = {};
    int grow = bm * 64 + arow;
    int old = rowmap[grow];
    float gt = gate[grow];
    const float* ap = A + (size_t)old * 192;
    __syncthreads();
    for (int kt = 0; kt < 192; kt += 16) {
        float4 av = *(const float4*)(ap + kt + aks);
        int kb = kt + aks;
        av.x = fmaxf((av.x * gas[kb + 0] + bes[kb + 0]) * gt, 0.f);
        av.y = fmaxf((av.y * gas[kb + 1] + bes[kb + 1]) * gt, 0.f);
        av.z = fmaxf((av.z * gas[kb + 2] + bes[kb + 2]) * gt, 0.f);
        av.w = fmaxf((av.w * gas[kb + 3] + bes[kb + 3]) * gt, 0.f);
        As[(aks + 0) * 68 + arow] = av.x;
        As[(aks + 1) * 68 + arow] = av.y;
        As[(aks + 2) * 68 + arow] = av.z;
        As[(aks + 3) * 68 + arow] = av.w;
        *(float4*)&Bs[brow * 68 + bns] = *(const float4*)(B + (size_t)(kt + brow) * 64 + bns);
        __syncthreads();
        #pragma unroll
        for (int kk = 0; kk < 16; ++kk) {
            float4 a4 = *(const float4*)&As[kk * 68 + (tm << 2)];
            float4 b4 = *(const float4*)&Bs[kk * 68 + (tn << 2)];
            float a_[4] = {a4.x, a4.y, a4.z, a4.w};
            float b_[4] = {b4.x, b4.y, b4.z, b4.w};
            #pragma unroll
            for (int i = 0; i < 4; ++i)
                #pragma unroll
                for (int j = 0; j < 4; ++j)
                    acc[i][j] += a_[i] * b_[j];
        }
        __syncthreads();
    }
    #pragma unroll
    for (int i = 0; i < 4; ++i) {
        int rr = bm * 64 + (tm << 2) + i;
        float4 o = {acc[i][0], acc[i][1], acc[i][2], acc[i][3]};
        *(float4*)(C + (size_t)rr * 64 + (tn << 2)) = o;
    }
}

// =====================================================================
// GAT1 attention (in place on hB) + tanh + BN1 partials. 64 threads.
// =====================================================================
__global__ __launch_bounds__(64) void gat1_att_bn(
    float* __restrict__ h, const int* __restrict__ parloc,
    const float* __restrict__ aw_s, const float* __restrict__ aw_d,
    const float* __restrict__ bias,
    float* __restrict__ psum, float* __restrict__ psq)
{
    __shared__ float hs[23 * 65];
    __shared__ float as_[23], ad_[23], aS[23], aP[23];
    __shared__ int parl[23];
    int g = blockIdx.x, t = threadIdx.x;
    float* base = h + (size_t)g * 23 * 64;
    for (int r = 0; r < 23; ++r) hs[r * 65 + t] = base[r * 64 + t];
    if (t < 23) parl[t] = parloc[g * 23 + t];
    __syncthreads();
    if (t < 46) {
        int r = t >> 1, sd = t & 1;
        const float* w = sd ? aw_d : aw_s;
        const float* row = &hs[r * 65];
        float s = 0.f;
        for (int c = 0; c < 64; ++c) s += row[c] * w[c];
        (sd ? ad_ : as_)[r] = s;
    }
    __syncthreads();
    if (t < 23) {
        int p = parl[t];
        if (p < 0) { aS[t] = 1.f; aP[t] = 0.f; }
        else {
            float ls = as_[t] + ad_[t]; ls = ls > 0 ? ls : 0.2f * ls;
            float lp = as_[p] + ad_[t]; lp = lp > 0 ? lp : 0.2f * lp;
            float m = fmaxf(ls, lp);
            float es = expf(ls - m), ep = expf(lp - m);
            float inv = 1.f / (es + ep);
            aS[t] = es * inv; aP[t] = ep * inv;
        }
    }
    __syncthreads();
    float bj = bias[t], s = 0.f, s2 = 0.f;
    for (int r = 0; r < 23; ++r) {
        int p = parl[r];
        float v = aS[r] * hs[r * 65 + t];
        if (p >= 0) v += aP[r] * hs[p * 65 + t];
        v = tanhf(v + bj);
        base[r * 64 + t] = v;
        s += v; s2 += v * v;
    }
    psum[(size_t)g * 64 + t] = s;
    psq [(size_t)g * 64 + t] = s2;
}

// =====================================================================
// Score1 + TopK(23->12) + gated-BN maxpool + relu + encoder MLP -> xenc
// =====================================================================
__global__ __launch_bounds__(128) void pool1_mlp(
    const float* __restrict__ h,
    const float* __restrict__ gw, const float* __restrict__ bw,
    const float* __restrict__ w,
    const float* __restrict__ ga, const float* __restrict__ be,
    const float* __restrict__ w1, const float* __restrict__ b1,
    const float* __restrict__ w2, const float* __restrict__ b2,
    float* __restrict__ xenc)
{
    __shared__ float hs[23 * 65];
    __shared__ float sc[23];
    __shared__ int keep[23];
    __shared__ float feat[64], t1[64];
    __shared__ float consts[2];
    int g = blockIdx.x, t = threadIdx.x;
    const float* base = h + (size_t)g * 23 * 64;
    {
        int c = t & 63;
        for (int r = t >> 6; r < 23; r += 2) hs[r * 65 + c] = base[r * 64 + c];
    }
    if (t < 64) {
        float ws = w[t] * w[t], bs = bw[t];
        for (int o = 32; o > 0; o >>= 1) { ws += __shfl_down(ws, o, 64); bs += __shfl_down(bs, o, 64); }
        if (t == 0) { consts[0] = 1.f / sqrtf(ws); consts[1] = bs; }
    }
    __syncthreads();
    if (t < 23) {
        const float* row = &hs[t * 65];
        float s = 0.f;
        for (int c = 0; c < 64; ++c) s += row[c] * gw[c];
        sc[t] = (s + consts[1]) * consts[0];
    }
    __syncthreads();
    if (t < 23) {
        float v = sc[t]; int rank = 0;
        for (int j = 0; j < 23; ++j) rank += (sc[j] > v) || (sc[j] == v && j < t);
        keep[t] = rank < 12;
    }
    __syncthreads();
    if (t < 23) sc[t] = tanhf(sc[t]);
    __syncthreads();
    if (t < 64) {
        float m = -1e30f, gac = ga[t], bec = be[t];
        for (int r = 0; r < 23; ++r)
            if (keep[r]) m = fmaxf(m, (hs[r * 65 + t] * gac + bec) * sc[r]);
        feat[t] = fmaxf(m, 0.f);
    }
    __syncthreads();
    if (t < 64) {
        float acc = b1[t];
        for (int c = 0; c < 64; ++c) acc += feat[c] * w1[c * 64 + t];
        t1[t] = fmaxf(acc, 0.f);
    }
    __syncthreads();
    float acc = b2[t];
    for (int j = 0; j < 64; ++j) acc += t1[j] * w2[j * 128 + t];
    xenc[(size_t)g * 128 + t] = acc;
}

// =====================================================================
// Generic tiled GEMM (stage B)
// =====================================================================
__global__ __launch_bounds__(256) void gemm_nn(
    const float* __restrict__ A, const float* __restrict__ B, float* __restrict__ C,
    int M, int N, int K)
{
    __shared__ float As[16 * 68];
    __shared__ float Bs[16 * 68];
    int tid = threadIdx.x;
    int bm = blockIdx.x, bn = blockIdx.y;
    int arow = tid >> 2, aks = (tid & 3) * 4;
    int brow = tid >> 4, bns = (tid & 15) * 4;
    int tm = tid >> 4, tn = tid & 15;
    float acc[4][4] = {};
    const float* ap = A + (size_t)(bm * 64 + arow) * K;
    for (int kt = 0; kt < K; kt += 16) {
        float4 av = *(const float4*)(ap + kt + aks);
        As[(aks + 0) * 68 + arow] = av.x;
        As[(aks + 1) * 68 + arow] = av.y;
        As[(aks + 2) * 68 + arow] = av.z;
        As[(aks + 3) * 68 + arow] = av.w;
        *(float4*)&Bs[brow * 68 + bns] = *(const float4*)(B + (size_t)(kt + brow) * N + bn * 64 + bns);
        __syncthreads();
        #pragma unroll
        for (int kk = 0; kk < 16; ++kk) {
            float4 a4 = *(const float4*)&As[kk * 68 + (tm << 2)];
            float4 b4 = *(const float4*)&Bs[kk * 68 + (tn << 2)];
            float a_[4] = {a4.x, a4.y, a4.z, a4.w};
            float b_[4] = {b4.x, b4.y, b4.z, b4.w};
            #pragma unroll
            for (int i = 0; i < 4; ++i)
                #pragma unroll
                for (int j = 0; j < 4; ++j)
                    acc[i][j] += a_[i] * b_[j];
        }
        __syncthreads();
    }
    #pragma unroll
    for (int i = 0; i < 4; ++i) {
        int r = bm * 64 + (tm << 2) + i;
        float4 o = {acc[i][0], acc[i][1], acc[i][2], acc[i][3]};
        *(float4*)(C + (size_t)r * N + bn * 64 + (tn << 2)) = o;
    }
}

// ---------------- BatchNorm (stage B) ----------------
__global__ void bn_stats(const float* __restrict__ X, int R,
                         float* __restrict__ sum, float* __restrict__ sumsq)
{
    int t = threadIdx.x;
    int C = blockDim.x;
    float s = 0.f, s2 = 0.f;
    for (int r = blockIdx.x; r < R; r += gridDim.x) {
        float v = X[(size_t)r * C + t];
        s += v; s2 += v * v;
    }
    atomicAdd(&sum[t], s);
    atomicAdd(&sumsq[t], s2);
}

__global__ void bn_apply(float* __restrict__ X, int R,
                         const float* __restrict__ sum, const float* __restrict__ sumsq,
                         const float* __restrict__ gam, const float* __restrict__ bet)
{
    int t = threadIdx.x;
    int C = blockDim.x;
    float invR = 1.f / (float)R;
    float mu = sum[t] * invR;
    float var = sumsq[t] * invR - mu * mu;
    float inv = 1.f / sqrtf(var + 1e-5f);
    float ga = gam[t] * inv;
    float be = bet[t] - mu * ga;
    for (int r = blockIdx.x; r < R; r += gridDim.x) {
        size_t idx = (size_t)r * C + t;
        X[idx] = X[idx] * ga + be;
    }
}

// ---------------- RGAT qi/kj precompute (3 heads) ----------------
__global__ __launch_bounds__(256) void rgat_qk3(
    const float* __restrict__ h0, const float* __restrict__ h1,
    const float* __restrict__ q, const float* __restrict__ k,
    float* __restrict__ qi, float* __restrict__ kj)
{
    int n = blockIdx.x, t = threadIdx.x;
    float p[12] = {};
    for (int d = t; d < HO3; d += 256) {
        float v0 = h0[(size_t)n * HO3 + d], v1 = h1[(size_t)n * HO3 + d];
        #pragma unroll
        for (int hh = 0; hh < 3; ++hh) {
            float qw = q[d * 3 + hh], kw = k[d * 3 + hh];
            p[hh]     += v0 * qw;  p[3 + hh] += v0 * kw;
            p[6 + hh] += v1 * qw;  p[9 + hh] += v1 * kw;
        }
    }
    __shared__ float red[4][12];
    #pragma unroll
    for (int i = 0; i < 12; ++i) {
        float x = p[i];
        for (int o = 32; o > 0; o >>= 1) x += __shfl_down(x, o, 64);
        if ((t & 63) == 0) red[t >> 6][i] = x;
    }
    __syncthreads();
    if (t < 12) {
        float s = red[0][t] + red[1][t] + red[2][t] + red[3][t];
        int rel = t / 6, rem = t % 6, isk = rem / 3, hh = rem % 3;
        float* dst = isk ? kj : qi;
        dst[((size_t)rel * NSTMT + n) * 3 + hh] = s;
    }
}

__global__ void edge_logits3(const int* __restrict__ src, const int* __restrict__ dst,
                             const int* __restrict__ et,
                             const float* __restrict__ qi, const float* __restrict__ kj,
                             float* __restrict__ logits)
{
    int e = blockIdx.x * 256 + threadIdx.x;
    if (e >= EST) return;
    int r = et[e], s = src[e], d = dst[e];
    #pragma unroll
    for (int hh = 0; hh < 3; ++hh) {
        float x = qi[((size_t)r * NSTMT + d) * 3 + hh] + kj[((size_t)r * NSTMT + s) * 3 + hh];
        logits[e * 3 + hh] = x > 0 ? x : 0.2f * x;
    }
}

// ---------------- CSR build ----------------
__global__ void count_deg(const int* __restrict__ dst, int* __restrict__ deg)
{
    int e = blockIdx.x * 256 + threadIdx.x;
    if (e < EST) atomicAdd(&deg[dst[e]], 1);
}

__global__ void scan_deg(const int* __restrict__ deg, int* __restrict__ offa)
{
    __shared__ int ts[1024];
    int t = threadIdx.x;
    int base = t * 8;
    int loc[8]; int s = 0;
    #pragma unroll
    for (int i = 0; i < 8; ++i) { loc[i] = s; s += deg[base + i]; }
    ts[t] = s;
    __syncthreads();
    for (int o = 1; o < 1024; o <<= 1) {
        int v = (t >= o) ? ts[t - o] : 0;
        __syncthreads();
        ts[t] += v;
        __syncthreads();
    }
    int prev = (t == 0) ? 0 : ts[t - 1];
    #pragma unroll
    for (int i = 0; i < 8; ++i) offa[base + i] = prev + loc[i];
    if (t == 1023) offa[8192] = ts[1023];
}

__global__ void scatter_csr(const int* __restrict__ dst, const int* __restrict__ offa,
                            int* __restrict__ cnt, int* __restrict__ csr)
{
    int e = blockIdx.x * 256 + threadIdx.x;
    if (e < EST) {
        int d = dst[e];
        int pos = offa[d] + atomicAdd(&cnt[d], 1);
        csr[pos] = e;
    }
}

// ---------------- RGAT0 aggregate ----------------
__global__ __launch_bounds__(256) void rgat_agg3(
    const float* __restrict__ h0, const float* __restrict__ h1,
    const int* __restrict__ offa, const int* __restrict__ csr,
    const int* __restrict__ src, const int* __restrict__ et,
    const float* __restrict__ logits, const float* __restrict__ bias,
    float* __restrict__ out)
{
    int n = blockIdx.x, t = threadIdx.x;
    int o0 = offa[n], deg = offa[n + 1] - o0;
    __shared__ float m[3], sden[3];
    __shared__ float al[64][3];
    __shared__ int esrc[64], erel[64];
    if (t < 3) {
        float mm = -1e30f;
        for (int i = 0; i < deg; ++i) mm = fmaxf(mm, logits[csr[o0 + i] * 3 + t]);
        float ss = 0.f;
        for (int i = 0; i < deg; ++i) ss += expf(logits[csr[o0 + i] * 3 + t] - mm);
        m[t] = mm; sden[t] = fmaxf(ss, 1e-16f);
    }
    __syncthreads();
    float acc0 = 0.f, acc1 = 0.f;
    for (int c0 = 0; c0 < deg; c0 += 64) {
        int cn = min(64, deg - c0);
        if (t < cn) { int e = csr[o0 + c0 + t]; esrc[t] = src[e]; erel[t] = et[e]; }
        if (t < cn * 3) {
            int ee = t / 3, hh = t % 3;
            int e = csr[o0 + c0 + ee];
            al[ee][hh] = expf(logits[e * 3 + hh] - m[hh]) / sden[hh];
        }
        __syncthreads();
        for (int i = 0; i < cn; ++i) {
            const float* hb = (erel[i] ? h1 : h0) + (size_t)esrc[i] * HO3;
            acc0 += al[i][t >> 7] * hb[t];
            if (t < 128) acc1 += al[i][(t + 256) >> 7] * hb[t + 256];
        }
        __syncthreads();
    }
    out[(size_t)n * HO3 + t] = tanhf(acc0 + bias[t]);
    if (t < 128) out[(size_t)n * HO3 + t + 256] = tanhf(acc1 + bias[t + 256]);
}

// ---------------- RGAT1 qi/kj ----------------
__global__ __launch_bounds__(128) void rgat_qk1(
    const float* __restrict__ h0, const float* __restrict__ h1,
    const float* __restrict__ q, const float* __restrict__ k,
    float* __restrict__ qi, float* __restrict__ kj)
{
    int n = blockIdx.x, t = threadIdx.x;
    float v0 = h0[(size_t)n * 128 + t], v1 = h1[(size_t)n * 128 + t];
    float p0 = v0 * q[t], p1 = v0 * k[t], p2 = v1 * q[t], p3 = v1 * k[t];
    __shared__ float red[2][4];
    for (int o = 32; o > 0; o >>= 1) {
        p0 += __shfl_down(p0, o, 64); p1 += __shfl_down(p1, o, 64);
        p2 += __shfl_down(p2, o, 64); p3 += __shfl_down(p3, o, 64);
    }
    if ((t & 63) == 0) { int w = t >> 6; red[w][0] = p0; red[w][1] = p1; red[w][2] = p2; red[w][3] = p3; }
    __syncthreads();
    if (t < 4) {
        float s = red[0][t] + red[1][t];
        if (t == 0) qi[n] = s;
        else if (t == 1) kj[n] = s;
        else if (t == 2) qi[NSTMT + n] = s;
        else kj[NSTMT + n] = s;
    }
}

__global__ void edge_logits1(const int* __restrict__ src, const int* __restrict__ dst,
                             const int* __restrict__ et,
                             const float* __restrict__ qi, const float* __restrict__ kj,
                             float* __restrict__ logits)
{
    int e = blockIdx.x * 256 + threadIdx.x;
    if (e >= EST) return;
    int r = et[e], s = src[e], d = dst[e];
    float x = qi[(size_t)r * NSTMT + d] + kj[(size_t)r * NSTMT + s];
    logits[e] = x > 0 ? x : 0.2f * x;
}

// ---------------- RGAT1 aggregate ----------------
__global__ __launch_bounds__(128) void rgat_agg1(
    const float* __restrict__ h0, const float* __restrict__ h1,
    const int* __restrict__ offa, const int* __restrict__ csr,
    const int* __restrict__ src, const int* __restrict__ et,
    const float* __restrict__ logits, const float* __restrict__ bias,
    float* __restrict__ out)
{
    int n = blockIdx.x, t = threadIdx.x;
    int o0 = offa[n], deg = offa[n + 1] - o0;
    __shared__ float m1, s1;
    __shared__ float al[64];
    __shared__ int esrc[64], erel[64];
    if (t == 0) {
        float mm = -1e30f;
        for (int i = 0; i < deg; ++i) mm = fmaxf(mm, logits[csr[o0 + i]]);
        float ss = 0.f;
        for (int i = 0; i < deg; ++i) ss += expf(logits[csr[o0 + i]] - mm);
        m1 = mm; s1 = fmaxf(ss, 1e-16f);
    }
    __syncthreads();
    float acc = 0.f;
    for (int c0 = 0; c0 < deg; c0 += 64) {
        int cn = min(64, deg - c0);
        if (t < cn) {
            int e = csr[o0 + c0 + t];
            esrc[t] = src[e]; erel[t] = et[e];
            al[t] = expf(logits[e] - m1) / s1;
        }
        __syncthreads();
        for (int i = 0; i < cn; ++i)
            acc += al[i] * ((erel[i] ? h1 : h0)[(size_t)esrc[i] * 128 + t]);
        __syncthreads();
    }
    out[(size_t)n * 128 + t] = tanhf(acc + bias[t]);
}

// ---------------- classifier ----------------
__global__ __launch_bounds__(128) void classifier(
    const float* __restrict__ x, const int* __restrict__ sel,
    const float* __restrict__ w1, const float* __restrict__ b1,
    const float* __restrict__ w2, const float* __restrict__ b2,
    float* __restrict__ out)
{
    __shared__ float row[128];
    __shared__ float t1[128];
    __shared__ float red[2];
    int b = blockIdx.x, t = threadIdx.x;
    int n = sel[b];
    row[t] = x[(size_t)n * 128 + t];
    __syncthreads();
    float acc = b1[t];
    for (int k = 0; k < 128; ++k) acc += row[k] * w1[k * 128 + t];
    t1[t] = fmaxf(acc, 0.f);
    __syncthreads();
    float p = t1[t] * w2[t];
    for (int o = 32; o > 0; o >>= 1) p += __shfl_down(p, o, 64);
    if ((t & 63) == 0) red[t >> 6] = p;
    __syncthreads();
    if (t == 0) {
        float z = red[0] + red[1] + b2[0];
        out[b] = 1.f / (1.f + expf(-z));
    }
}

// ---------------- workspace layout (bytes) ----------------
constexpr size_t OFF_HA     = 0;                       // 201326592
constexpr size_t OFF_BN0    = 201326592;               // 4*768
constexpr size_t OFF_BN1    = OFF_BN0 + 3072;          // 4*256
constexpr size_t OFF_OLDROW = OFF_BN1 + 1024;
constexpr size_t OFF_GATE   = OFF_OLDROW + 753664;
constexpr size_t OFF_PARLOC = OFF_GATE + 753664;
constexpr size_t OFF_HB     = OFF_PARLOC + 753664;     // 48234496 (psum0/psq0 alias)
constexpr size_t OFF_XENC   = OFF_HB + 48234496;       // 4194304 (psum1/psq1 alias)
constexpr size_t OFF_BNSUM  = OFF_XENC + 4194304;
constexpr size_t OFF_BNSQ   = OFF_BNSUM + 1536;
constexpr size_t WS_NEEDED  = OFF_BNSQ + 1536;
// stage-B aliases inside hA (dead after gemm_gather):
constexpr size_t OFF_H0R  = 0;
constexpr size_t OFF_H1R  = 12582912;
constexpr size_t OFF_OUT0 = 25165824;
constexpr size_t OFF_G0   = 37748736;
constexpr size_t OFF_G1   = 41943040;
constexpr size_t OFF_OUT1 = 46137344;
constexpr size_t OFF_QI3  = 50331648;
constexpr size_t OFF_KJ3  = 50528256;
constexpr size_t OFF_LG3  = 50724864;
constexpr size_t OFF_QI1  = 51118080;
constexpr size_t OFF_KJ1  = 51183616;
constexpr size_t OFF_LG1  = 51249152;
constexpr size_t OFF_DEG  = 51380224;
constexpr size_t OFF_OFFA = 51412992;
constexpr size_t OFF_CNT  = 51446016;
constexpr size_t OFF_CSR  = 51478784;

extern "C" void kernel_launch(void* const* d_in, const int* in_sizes, int n_in,
                              void* d_out, int out_size, void* d_ws, size_t ws_size,
                              hipStream_t stream)
{
    if (n_in < 41 || ws_size < WS_NEEDED) return;

    const float* ast_x    = (const float*)d_in[0];
    const int*   ast_src  = (const int*)d_in[1];
    const int*   stmt_src = (const int*)d_in[3];
    const int*   stmt_dst = (const int*)d_in[4];
    const int*   stmt_et  = (const int*)d_in[5];
    const int*   sel      = (const int*)d_in[6];
    const float* gat0_W    = (const float*)d_in[7];
    const float* gat0_asrc = (const float*)d_in[8];
    const float* gat0_adst = (const float*)d_in[9];
    const float* gat0_b    = (const float*)d_in[10];
    const float* bn0_g     = (const float*)d_in[11];
    const float* bn0_b     = (const float*)d_in[12];
    const float* pool0_w   = (const float*)d_in[13];
    const float* gat1_W    = (const float*)d_in[14];
    const float* gat1_asrc = (const float*)d_in[15];
    const float* gat1_adst = (const float*)d_in[16];
    const float* gat1_b    = (const float*)d_in[17];
    const float* bn1_g     = (const float*)d_in[18];
    const float* bn1_b     = (const float*)d_in[19];
    const float* pool1_w   = (const float*)d_in[20];
    const float* enc_w1    = (const float*)d_in[21];
    const float* enc_b1    = (const float*)d_in[22];
    const float* enc_w2    = (const float*)d_in[23];
    const float* enc_b2    = (const float*)d_in[24];
    const float* rgat0_W   = (const float*)d_in[25];
    const float* rgat0_q   = (const float*)d_in[26];
    const float* rgat0_k   = (const float*)d_in[27];
    const float* rgat0_b   = (const float*)d_in[28];
    const float* bnc0_g    = (const float*)d_in[29];
    const float* bnc0_b    = (const float*)d_in[30];
    const float* rgat1_W   = (const float*)d_in[31];
    const float* rgat1_q   = (const float*)d_in[32];
    const float* rgat1_k   = (const float*)d_in[33];
    const float* rgat1_b   = (const float*)d_in[34];
    const float* bnc1_g    = (const float*)d_in[35];
    const float* bnc1_b    = (const float*)d_in[36];
    const float* clf_w1    = (const float*)d_in[37];
    const float* clf_b1    = (const float*)d_in[38];
    const float* clf_w2    = (const float*)d_in[39];
    const float* clf_b2    = (const float*)d_in[40];

    char* ws = (char*)d_ws;
    float* hA     = (float*)(ws + OFF_HA);
    float* ga0    = (float*)(ws + OFF_BN0);
    float* be0    = ga0 + 192;
    float* gw0    = be0 + 192;
    float* bw0    = gw0 + 192;
    float* ga1    = (float*)(ws + OFF_BN1);
    float* be1    = ga1 + 64;
    float* gw1    = be1 + 64;
    float* bw1    = gw1 + 64;
    int*   oldrow = (int*)(ws + OFF_OLDROW);
    float* gate23 = (float*)(ws + OFF_GATE);
    int*   parloc = (int*)(ws + OFF_PARLOC);
    float* hB     = (float*)(ws + OFF_HB);
    float* psum0  = (float*)(ws + OFF_HB);           // [2048][192] alias
    float* psq0   = psum0 + 192 * 2048;
    float* xenc   = (float*)(ws + OFF_XENC);
    float* psum1  = (float*)(ws + OFF_XENC);         // [8192][64] alias
    float* psq1   = psum1 + 64 * 8192;
    float* bnsum  = (float*)(ws + OFF_BNSUM);
    float* bnsq   = (float*)(ws + OFF_BNSQ);

    float* h0r  = (float*)(ws + OFF_H0R);
    float* h1r  = (float*)(ws + OFF_H1R);
    float* out0 = (float*)(ws + OFF_OUT0);
    float* g0   = (float*)(ws + OFF_G0);
    float* g1   = (float*)(ws + OFF_G1);
    float* out1 = (float*)(ws + OFF_OUT1);
    float* qi3  = (float*)(ws + OFF_QI3);
    float* kj3  = (float*)(ws + OFF_KJ3);
    float* lg3  = (float*)(ws + OFF_LG3);
    float* qi1  = (float*)(ws + OFF_QI1);
    float* kj1  = (float*)(ws + OFF_KJ1);
    float* lg1  = (float*)(ws + OFF_LG1);
    int*   deg  = (int*)(ws + OFF_DEG);
    int*   offa = (int*)(ws + OFF_OFFA);
    int*   cnt  = (int*)(ws + OFF_CNT);
    int*   csr  = (int*)(ws + OFF_CSR);

    // ---- Stage A ----
    fused_gat0<<<2048, 256, 0, stream>>>(ast_x, gat0_W, ast_src, gat0_asrc, gat0_adst,
                                         gat0_b, hA, psum0, psq0);
    bn_finalize<<<192, 256, 0, stream>>>(psum0, psq0, 2048, 192, (float)N0,
                                         bn0_g, bn0_b, pool0_w, ga0, be0, gw0, bw0);
    score_topk0<<<G, 256, 0, stream>>>(hA, ast_src, gw0, bw0, pool0_w,
                                       oldrow, gate23, parloc);
    gemm_gather<<<N1 / 64, 256, 0, stream>>>(hA, gat1_W, hB, oldrow, gate23, ga0, be0);
    gat1_att_bn<<<G, 64, 0, stream>>>(hB, parloc, gat1_asrc, gat1_adst, gat1_b,
                                      psum1, psq1);
    bn_finalize<<<64, 256, 0, stream>>>(psum1, psq1, 8192, 64, (float)N1,
                                        bn1_g, bn1_b, pool1_w, ga1, be1, gw1, bw1);
    pool1_mlp<<<G, 128, 0, stream>>>(hB, gw1, bw1, pool1_w, ga1, be1,
                                     enc_w1, enc_b1, enc_w2, enc_b2, xenc);

    // ---- Stage B ----
    gemm_nn<<<dim3(NSTMT / 64, HO3 / 64), 256, 0, stream>>>(xenc, rgat0_W, h0r, NSTMT, HO3, ENC);
    gemm_nn<<<dim3(NSTMT / 64, HO3 / 64), 256, 0, stream>>>(xenc, rgat0_W + (size_t)ENC * HO3, h1r, NSTMT, HO3, ENC);
    rgat_qk3<<<NSTMT, 256, 0, stream>>>(h0r, h1r, rgat0_q, rgat0_k, qi3, kj3);
    edge_logits3<<<EST / 256, 256, 0, stream>>>(stmt_src, stmt_dst, stmt_et, qi3, kj3, lg3);
    hipMemsetAsync(deg, 0, 32768, stream);
    hipMemsetAsync(cnt, 0, 32768, stream);
    count_deg<<<EST / 256, 256, 0, stream>>>(stmt_dst, deg);
    scan_deg<<<1, 1024, 0, stream>>>(deg, offa);
    scatter_csr<<<EST / 256, 256, 0, stream>>>(stmt_dst, offa, cnt, csr);
    rgat_agg3<<<NSTMT, 256, 0, stream>>>(h0r, h1r, offa, csr, stmt_src, stmt_et, lg3, rgat0_b, out0);
    hipMemsetAsync(bnsum, 0, 3072, stream);
    bn_stats<<<256, HO3, 0, stream>>>(out0, NSTMT, bnsum, bnsq);
    bn_apply<<<256, HO3, 0, stream>>>(out0, NSTMT, bnsum, bnsq, bnc0_g, bnc0_b);
    gemm_nn<<<dim3(NSTMT / 64, HOUT / 64), 256, 0, stream>>>(out0, rgat1_W, g0, NSTMT, HOUT, HO3);
    gemm_nn<<<dim3(NSTMT / 64, HOUT / 64), 256, 0, stream>>>(out0, rgat1_W + (size_t)HO3 * HOUT, g1, NSTMT, HOUT, HO3);
    rgat_qk1<<<NSTMT, 128, 0, stream>>>(g0, g1, rgat1_q, rgat1_k, qi1, kj1);
    edge_logits1<<<EST / 256, 256, 0, stream>>>(stmt_src, stmt_dst, stmt_et, qi1, kj1, lg1);
    rgat_agg1<<<NSTMT, 128, 0, stream>>>(g0, g1, offa, csr, stmt_src, stmt_et, lg1, rgat1_b, out1);
    hipMemsetAsync(bnsum, 0, 3072, stream);
    bn_stats<<<256, HOUT, 0, stream>>>(out1, NSTMT, bnsum, bnsq);
    bn_apply<<<256, HOUT, 0, stream>>>(out1, NSTMT, bnsum, bnsq, bnc1_g, bnc1_b);
    classifier<<<NSEL, 128, 0, stream>>>(out1, sel, clf_w1, clf_b1, clf_w2, clf_b2, (float*)d_out);
}

// Round 10
// 995.623 us; speedup vs baseline: 11.1440x; 1.0544x over previous
//
#include <hip/hip_runtime.h>
#include <cstddef>
#include <cstdint>

// ---------------- problem constants ----------------
constexpr int G      = 8192;
constexpr int NAST   = 32;
constexpr int N0     = G * NAST;    // 262144
constexpr int D_EMB  = 128;
constexpr int C0     = 192;         // 3 * H_IN
constexpr int H_IN   = 64;
constexpr int K0     = 23;          // ceil(0.7*32)
constexpr int N1     = G * K0;      // 188416
constexpr int K1     = 12;          // ceil(0.5*23)
constexpr int ENC    = 128;
constexpr int NSTMT  = 8192;
constexpr int EST    = 32768;
constexpr int HO3    = 384;
constexpr int HOUT   = 128;
constexpr int NSEL   = 4096;

// =====================================================================
// Fused GAT0 (r3-validated geometry + B-swizzle):
// per-block = 2 AST graphs (64 rows) x 192 cols, K=128. 192 threads,
// 8x8 register tiles (VGPR 76, no spill — measured r3).
// B stored in LDS with split-row layout: cols >= 96 shifted +4 floats,
// turning the 6-way bank conflict on Bs reads (measured 1.685e7
// conflict cycles, r3) into a uniform 3-way (~free).
// =====================================================================
__global__ __launch_bounds__(192) void fused_gat0(
    const float* __restrict__ X, const float* __restrict__ W,
    const int* __restrict__ ast_src,
    const float* __restrict__ asrc_w, const float* __restrict__ adst_w,
    const float* __restrict__ bias,
    float* __restrict__ out, float* __restrict__ psum, float* __restrict__ psq)
{
    __shared__ float smem[13376];      // 53504 B
    float* As = smem;                  // [32][68] k-major
    float* Bs = smem + 2176;           // [32][200] k-major, swizzled cols
    int tid = threadIdx.x;
    int b = blockIdx.x;
    int row0 = b * 64;
    int tm = tid / 24;                 // 0..7 : row group (8 rows)
    int tn = tid % 24;                 // 0..23: col group (8 cols)

    float acc[8][8] = {};
    const int bof = tn * 8 + ((tn >= 12) ? 4 : 0);   // swizzled read base

    for (int kt = 0; kt < 128; kt += 32) {
        // stage A tile: 64 rows x 32 k  (scatter to k-major)
        for (int i = tid; i < 512; i += 192) {
            int r = i & 63, q = i >> 6;
            float4 v = *(const float4*)(X + (size_t)(row0 + r) * 128 + kt + q * 4);
            As[(q * 4 + 0) * 68 + r] = v.x;
            As[(q * 4 + 1) * 68 + r] = v.y;
            As[(q * 4 + 2) * 68 + r] = v.z;
            As[(q * 4 + 3) * 68 + r] = v.w;
        }
        // stage B tile: 32 k x 192 n, swizzled store (cols>=96 -> +4)
        for (int i = tid; i < 1536; i += 192) {
            int k = i / 48, c4 = (i % 48) * 4;
            int sc = c4 + ((c4 >= 96) ? 4 : 0);
            *(float4*)&Bs[k * 200 + sc] = *(const float4*)(W + (size_t)(kt + k) * 192 + c4);
        }
        __syncthreads();
        #pragma unroll 4
        for (int kk = 0; kk < 32; ++kk) {
            float4 a0 = *(const float4*)&As[kk * 68 + tm * 8];
            float4 a1 = *(const float4*)&As[kk * 68 + tm * 8 + 4];
            float4 b0 = *(const float4*)&Bs[kk * 200 + bof];
            float4 b1 = *(const float4*)&Bs[kk * 200 + bof + 4];
            float a_[8] = {a0.x, a0.y, a0.z, a0.w, a1.x, a1.y, a1.z, a1.w};
            float b_[8] = {b0.x, b0.y, b0.z, b0.w, b1.x, b1.y, b1.z, b1.w};
            #pragma unroll
            for (int i = 0; i < 8; ++i)
                #pragma unroll
                for (int j = 0; j < 8; ++j)
                    acc[i][j] += a_[i] * b_[j];
        }
        __syncthreads();
    }

    // ---- phase 2: attention epilogue (2 graphs, 64 rows in one pass) ----
    float* Cs  = smem;                 // [64][196]
    float* as_ = smem + 12544;         // [64][3]
    float* ad_ = as_ + 192;
    float* aS  = ad_ + 192;
    float* aP  = aS + 192;
    int*  parl = (int*)(aP + 192);     // [64]

    #pragma unroll
    for (int i = 0; i < 8; ++i) {
        *(float4*)&Cs[(tm * 8 + i) * 196 + tn * 8]     = *(float4*)&acc[i][0];
        *(float4*)&Cs[(tm * 8 + i) * 196 + tn * 8 + 4] = *(float4*)&acc[i][4];
    }
    if (tid < 62) {
        int q = tid / 31, j = tid % 31 + 1;
        int g = 2 * b + q;
        parl[q * 32 + j] = ast_src[(size_t)g * 31 + j - 1] - g * 32 + q * 32;
    }
    if (tid < 2) parl[tid * 32] = -1;
    __syncthreads();

    for (int task = tid; task < 384; task += 192) {
        int r = task / 6, q6 = task % 6, hh = q6 >> 1, sd = q6 & 1;
        const float* w = (sd ? adst_w : asrc_w) + hh * 64;
        const float* crow = &Cs[r * 196 + hh * 64];
        float s = 0.f;
        for (int c = 0; c < 64; ++c) s += crow[c] * w[c];
        (sd ? ad_ : as_)[r * 3 + hh] = s;
    }
    __syncthreads();
    if (tid < 192) {
        int r = tid / 3, hh = tid % 3, p = parl[r];
        if (p < 0) { aS[r * 3 + hh] = 1.f; aP[r * 3 + hh] = 0.f; }
        else {
            float ls = as_[r * 3 + hh] + ad_[r * 3 + hh]; ls = ls > 0 ? ls : 0.2f * ls;
            float lp = as_[p * 3 + hh] + ad_[r * 3 + hh]; lp = lp > 0 ? lp : 0.2f * lp;
            float m = fmaxf(ls, lp);
            float es = expf(ls - m), ep = expf(lp - m);
            float inv = 1.f / (es + ep);
            aS[r * 3 + hh] = es * inv; aP[r * 3 + hh] = ep * inv;
        }
    }
    __syncthreads();
    {
        int j = tid, hh = j >> 6;
        float bj = bias[j];
        float s = 0.f, s2 = 0.f;
        for (int r = 0; r < 64; ++r) {
            int p = parl[r];
            float v = aS[r * 3 + hh] * Cs[r * 196 + j];
            if (p >= 0) v += aP[r * 3 + hh] * Cs[p * 196 + j];
            v = tanhf(v + bj);
            out[(size_t)(row0 + r) * 192 + j] = v;
            s += v; s2 += v * v;
        }
        psum[(size_t)b * 192 + j] = s;   // coalesced [block][col]
        psq [(size_t)b * 192 + j] = s2;
    }
}

// =====================================================================
// BN finalize: column j of [nb][C] partials -> ga/be + folded gw/bw.
// =====================================================================
__global__ __launch_bounds__(256) void bn_finalize(
    const float* __restrict__ psum, const float* __restrict__ psq, int nb, int C, float R,
    const float* __restrict__ gamma, const float* __restrict__ beta,
    const float* __restrict__ w,
    float* __restrict__ ga, float* __restrict__ be,
    float* __restrict__ gw, float* __restrict__ bw)
{
    int j = blockIdx.x, t = threadIdx.x;
    float s = 0.f, s2 = 0.f;
    for (int i = t; i < nb; i += 256) {
        s  += psum[(size_t)i * C + j];
        s2 += psq [(size_t)i * C + j];
    }
    __shared__ float r1[4], r2[4];
    for (int o = 32; o > 0; o >>= 1) { s += __shfl_down(s, o, 64); s2 += __shfl_down(s2, o, 64); }
    if ((t & 63) == 0) { r1[t >> 6] = s; r2[t >> 6] = s2; }
    __syncthreads();
    if (t == 0) {
        float S = r1[0] + r1[1] + r1[2] + r1[3];
        float S2 = r2[0] + r2[1] + r2[2] + r2[3];
        float mu = S / R, var = S2 / R - mu * mu;
        float inv = 1.f / sqrtf(var + 1e-5f);
        float gaj = gamma[j] * inv, bej = beta[j] - mu * gaj;
        ga[j] = gaj; be[j] = bej; gw[j] = gaj * w[j]; bw[j] = bej * w[j];
    }
}

// =====================================================================
// Score + TopK(32->23) + parent remap. Reads raw hA once.
// =====================================================================
__global__ __launch_bounds__(256) void score_topk0(
    const float* __restrict__ hA, const int* __restrict__ ast_src,
    const float* __restrict__ gw, const float* __restrict__ bw,
    const float* __restrict__ w,
    int* __restrict__ oldrow, float* __restrict__ gate23, int* __restrict__ parloc)
{
    __shared__ float swv[192];
    __shared__ float sc[32];
    __shared__ int nid[32];
    __shared__ float wparts[4], bparts[4];
    int g = blockIdx.x, t = threadIdx.x;
    if (t < 192) swv[t] = gw[t];
    float ws = (t < 192) ? w[t] * w[t] : 0.f;
    float bs = (t < 192) ? bw[t] : 0.f;
    for (int o = 32; o > 0; o >>= 1) { ws += __shfl_down(ws, o, 64); bs += __shfl_down(bs, o, 64); }
    if ((t & 63) == 0) { wparts[t >> 6] = ws; bparts[t >> 6] = bs; }
    __syncthreads();
    float invn = 1.f / sqrtf(wparts[0] + wparts[1] + wparts[2] + wparts[3]);
    float sb = bparts[0] + bparts[1] + bparts[2] + bparts[3];

    int r = t >> 3, j0 = (t & 7) * 24;
    const float4* row4 = (const float4*)(hA + ((size_t)g * 32 + r) * 192 + j0);
    const float4* sw4 = (const float4*)(swv + j0);
    float s = 0.f;
    #pragma unroll
    for (int u = 0; u < 6; ++u) {
        float4 a = row4[u], bv = sw4[u];
        s += a.x * bv.x + a.y * bv.y + a.z * bv.z + a.w * bv.w;
    }
    for (int o = 4; o > 0; o >>= 1) s += __shfl_down(s, o, 8);
    if ((t & 7) == 0) sc[r] = (s + sb) * invn;
    __syncthreads();
    if (t < 32) {
        float v = sc[t]; int rank = 0;
        for (int j = 0; j < 32; ++j) rank += (sc[j] > v) || (sc[j] == v && j < t);
        nid[t] = (rank < 23) ? rank : -1;
    }
    __syncthreads();
    if (t < 32 && nid[t] >= 0) {
        int rank = nid[t];
        oldrow[g * 23 + rank] = g * 32 + t;
        gate23[g * 23 + rank] = tanhf(sc[t]);
        int pl = -1;
        if (t > 0) {
            int p = ast_src[(size_t)g * 31 + t - 1] - g * 32;
            pl = nid[p];
        }
        parloc[g * 23 + rank] = pl;
    }
}

// =====================================================================
// Gather-GEMM: hB[N1,64] = relu((hA[old]*ga+be)*gate) @ gat1_W[192,64]
// =====================================================================
__global__ __launch_bounds__(256) void gemm_gather(
    const float* __restrict__ A, const float* __restrict__ B, float* __restrict__ C,
    const int* __restrict__ rowmap, const float* __restrict__ gate,
    const float* __restrict__ ga, const float* __restrict__ be)
{
    __shared__ float As[16 * 68];
    __shared__ float Bs[16 * 68];
    __shared__ float gas[192], bes[192];
    int tid = threadIdx.x, bm = blockIdx.x;
    if (tid < 192) { gas[tid] = ga[tid]; bes[tid] = be[tid]; }
    int arow = tid >> 2, aks = (tid & 3) * 4;
    int brow = tid >> 4, bns = (tid & 15) * 4;
    int tm = tid >> 4, tn = tid & 15;
    float acc[4][4] = {};
    int grow = bm * 64 + arow;
    int old = rowmap[grow];
    float gt = gate[grow];
    const float* ap = A + (size_t)old * 192;
    __syncthreads();
    for (int kt = 0; kt < 192; kt += 16) {
        float4 av = *(const float4*)(ap + kt + aks);
        int kb = kt + aks;
        av.x = fmaxf((av.x * gas[kb + 0] + bes[kb + 0]) * gt, 0.f);
        av.y = fmaxf((av.y * gas[kb + 1] + bes[kb + 1]) * gt, 0.f);
        av.z = fmaxf((av.z * gas[kb + 2] + bes[kb + 2]) * gt, 0.f);
        av.w = fmaxf((av.w * gas[kb + 3] + bes[kb + 3]) * gt, 0.f);
        As[(aks + 0) * 68 + arow] = av.x;
        As[(aks + 1) * 68 + arow] = av.y;
        As[(aks + 2) * 68 + arow] = av.z;
        As[(aks + 3) * 68 + arow] = av.w;
        *(float4*)&Bs[brow * 68 + bns] = *(const float4*)(B + (size_t)(kt + brow) * 64 + bns);
        __syncthreads();
        #pragma unroll
        for (int kk = 0; kk < 16; ++kk) {
            float4 a4 = *(const float4*)&As[kk * 68 + (tm << 2)];
            float4 b4 = *(const float4*)&Bs[kk * 68 + (tn << 2)];
            float a_[4] = {a4.x, a4.y, a4.z, a4.w};
            float b_[4] = {b4.x, b4.y, b4.z, b4.w};
            #pragma unroll
            for (int i = 0; i < 4; ++i)
                #pragma unroll
                for (int j = 0; j < 4; ++j)
                    acc[i][j] += a_[i] * b_[j];
        }
        __syncthreads();
    }
    #pragma unroll
    for (int i = 0; i < 4; ++i) {
        int rr = bm * 64 + (tm << 2) + i;
        float4 o = {acc[i][0], acc[i][1], acc[i][2], acc[i][3]};
        *(float4*)(C + (size_t)rr * 64 + (tn << 2)) = o;
    }
}

// =====================================================================
// GAT1 attention (in place on hB) + tanh + BN1 partials. 64 threads.
// =====================================================================
__global__ __launch_bounds__(64) void gat1_att_bn(
    float* __restrict__ h, const int* __restrict__ parloc,
    const float* __restrict__ aw_s, const float* __restrict__ aw_d,
    const float* __restrict__ bias,
    float* __restrict__ psum, float* __restrict__ psq)
{
    __shared__ float hs[23 * 65];
    __shared__ float as_[23], ad_[23], aS[23], aP[23];
    __shared__ int parl[23];
    int g = blockIdx.x, t = threadIdx.x;
    float* base = h + (size_t)g * 23 * 64;
    for (int r = 0; r < 23; ++r) hs[r * 65 + t] = base[r * 64 + t];
    if (t < 23) parl[t] = parloc[g * 23 + t];
    __syncthreads();
    if (t < 46) {
        int r = t >> 1, sd = t & 1;
        const float* w = sd ? aw_d : aw_s;
        const float* row = &hs[r * 65];
        float s = 0.f;
        for (int c = 0; c < 64; ++c) s += row[c] * w[c];
        (sd ? ad_ : as_)[r] = s;
    }
    __syncthreads();
    if (t < 23) {
        int p = parl[t];
        if (p < 0) { aS[t] = 1.f; aP[t] = 0.f; }
        else {
            float ls = as_[t] + ad_[t]; ls = ls > 0 ? ls : 0.2f * ls;
            float lp = as_[p] + ad_[t]; lp = lp > 0 ? lp : 0.2f * lp;
            float m = fmaxf(ls, lp);
            float es = expf(ls - m), ep = expf(lp - m);
            float inv = 1.f / (es + ep);
            aS[t] = es * inv; aP[t] = ep * inv;
        }
    }
    __syncthreads();
    float bj = bias[t], s = 0.f, s2 = 0.f;
    for (int r = 0; r < 23; ++r) {
        int p = parl[r];
        float v = aS[r] * hs[r * 65 + t];
        if (p >= 0) v += aP[r] * hs[p * 65 + t];
        v = tanhf(v + bj);
        base[r * 64 + t] = v;
        s += v; s2 += v * v;
    }
    psum[(size_t)g * 64 + t] = s;
    psq [(size_t)g * 64 + t] = s2;
}

// =====================================================================
// Score1 + TopK(23->12) + gated-BN maxpool + relu + encoder MLP -> xenc
// =====================================================================
__global__ __launch_bounds__(128) void pool1_mlp(
    const float* __restrict__ h,
    const float* __restrict__ gw, const float* __restrict__ bw,
    const float* __restrict__ w,
    const float* __restrict__ ga, const float* __restrict__ be,
    const float* __restrict__ w1, const float* __restrict__ b1,
    const float* __restrict__ w2, const float* __restrict__ b2,
    float* __restrict__ xenc)
{
    __shared__ float hs[23 * 65];
    __shared__ float sc[23];
    __shared__ int keep[23];
    __shared__ float feat[64], t1[64];
    __shared__ float consts[2];
    int g = blockIdx.x, t = threadIdx.x;
    const float* base = h + (size_t)g * 23 * 64;
    {
        int c = t & 63;
        for (int r = t >> 6; r < 23; r += 2) hs[r * 65 + c] = base[r * 64 + c];
    }
    if (t < 64) {
        float ws = w[t] * w[t], bs = bw[t];
        for (int o = 32; o > 0; o >>= 1) { ws += __shfl_down(ws, o, 64); bs += __shfl_down(bs, o, 64); }
        if (t == 0) { consts[0] = 1.f / sqrtf(ws); consts[1] = bs; }
    }
    __syncthreads();
    if (t < 23) {
        const float* row = &hs[t * 65];
        float s = 0.f;
        for (int c = 0; c < 64; ++c) s += row[c] * gw[c];
        sc[t] = (s + consts[1]) * consts[0];
    }
    __syncthreads();
    if (t < 23) {
        float v = sc[t]; int rank = 0;
        for (int j = 0; j < 23; ++j) rank += (sc[j] > v) || (sc[j] == v && j < t);
        keep[t] = rank < 12;
    }
    __syncthreads();
    if (t < 23) sc[t] = tanhf(sc[t]);
    __syncthreads();
    if (t < 64) {
        float m = -1e30f, gac = ga[t], bec = be[t];
        for (int r = 0; r < 23; ++r)
            if (keep[r]) m = fmaxf(m, (hs[r * 65 + t] * gac + bec) * sc[r]);
        feat[t] = fmaxf(m, 0.f);
    }
    __syncthreads();
    if (t < 64) {
        float acc = b1[t];
        for (int c = 0; c < 64; ++c) acc += feat[c] * w1[c * 64 + t];
        t1[t] = fmaxf(acc, 0.f);
    }
    __syncthreads();
    float acc = b2[t];
    for (int j = 0; j < 64; ++j) acc += t1[j] * w2[j * 128 + t];
    xenc[(size_t)g * 128 + t] = acc;
}

// =====================================================================
// Generic tiled GEMM (stage B)
// =====================================================================
__global__ __launch_bounds__(256) void gemm_nn(
    const float* __restrict__ A, const float* __restrict__ B, float* __restrict__ C,
    int M, int N, int K)
{
    __shared__ float As[16 * 68];
    __shared__ float Bs[16 * 68];
    int tid = threadIdx.x;
    int bm = blockIdx.x, bn = blockIdx.y;
    int arow = tid >> 2, aks = (tid & 3) * 4;
    int brow = tid >> 4, bns = (tid & 15) * 4;
    int tm = tid >> 4, tn = tid & 15;
    float acc[4][4] = {};
    const float* ap = A + (size_t)(bm * 64 + arow) * K;
    for (int kt = 0; kt < K; kt += 16) {
        float4 av = *(const float4*)(ap + kt + aks);
        As[(aks + 0) * 68 + arow] = av.x;
        As[(aks + 1) * 68 + arow] = av.y;
        As[(aks + 2) * 68 + arow] = av.z;
        As[(aks + 3) * 68 + arow] = av.w;
        *(float4*)&Bs[brow * 68 + bns] = *(const float4*)(B + (size_t)(kt + brow) * N + bn * 64 + bns);
        __syncthreads();
        #pragma unroll
        for (int kk = 0; kk < 16; ++kk) {
            float4 a4 = *(const float4*)&As[kk * 68 + (tm << 2)];
            float4 b4 = *(const float4*)&Bs[kk * 68 + (tn << 2)];
            float a_[4] = {a4.x, a4.y, a4.z, a4.w};
            float b_[4] = {b4.x, b4.y, b4.z, b4.w};
            #pragma unroll
            for (int i = 0; i < 4; ++i)
                #pragma unroll
                for (int j = 0; j < 4; ++j)
                    acc[i][j] += a_[i] * b_[j];
        }
        __syncthreads();
    }
    #pragma unroll
    for (int i = 0; i < 4; ++i) {
        int r = bm * 64 + (tm << 2) + i;
        float4 o = {acc[i][0], acc[i][1], acc[i][2], acc[i][3]};
        *(float4*)(C + (size_t)r * N + bn * 64 + (tn << 2)) = o;
    }
}

// ---------------- BatchNorm (stage B) ----------------
__global__ void bn_stats(const float* __restrict__ X, int R,
                         float* __restrict__ sum, float* __restrict__ sumsq)
{
    int t = threadIdx.x;
    int C = blockDim.x;
    float s = 0.f, s2 = 0.f;
    for (int r = blockIdx.x; r < R; r += gridDim.x) {
        float v = X[(size_t)r * C + t];
        s += v; s2 += v * v;
    }
    atomicAdd(&sum[t], s);
    atomicAdd(&sumsq[t], s2);
}

__global__ void bn_apply(float* __restrict__ X, int R,
                         const float* __restrict__ sum, const float* __restrict__ sumsq,
                         const float* __restrict__ gam, const float* __restrict__ bet)
{
    int t = threadIdx.x;
    int C = blockDim.x;
    float invR = 1.f / (float)R;
    float mu = sum[t] * invR;
    float var = sumsq[t] * invR - mu * mu;
    float inv = 1.f / sqrtf(var + 1e-5f);
    float ga = gam[t] * inv;
    float be = bet[t] - mu * ga;
    for (int r = blockIdx.x; r < R; r += gridDim.x) {
        size_t idx = (size_t)r * C + t;
        X[idx] = X[idx] * ga + be;
    }
}

// ---------------- RGAT qi/kj precompute (3 heads) ----------------
__global__ __launch_bounds__(256) void rgat_qk3(
    const float* __restrict__ h0, const float* __restrict__ h1,
    const float* __restrict__ q, const float* __restrict__ k,
    float* __restrict__ qi, float* __restrict__ kj)
{
    int n = blockIdx.x, t = threadIdx.x;
    float p[12] = {};
    for (int d = t; d < HO3; d += 256) {
        float v0 = h0[(size_t)n * HO3 + d], v1 = h1[(size_t)n * HO3 + d];
        #pragma unroll
        for (int hh = 0; hh < 3; ++hh) {
            float qw = q[d * 3 + hh], kw = k[d * 3 + hh];
            p[hh]     += v0 * qw;  p[3 + hh] += v0 * kw;
            p[6 + hh] += v1 * qw;  p[9 + hh] += v1 * kw;
        }
    }
    __shared__ float red[4][12];
    #pragma unroll
    for (int i = 0; i < 12; ++i) {
        float x = p[i];
        for (int o = 32; o > 0; o >>= 1) x += __shfl_down(x, o, 64);
        if ((t & 63) == 0) red[t >> 6][i] = x;
    }
    __syncthreads();
    if (t < 12) {
        float s = red[0][t] + red[1][t] + red[2][t] + red[3][t];
        int rel = t / 6, rem = t % 6, isk = rem / 3, hh = rem % 3;
        float* dst = isk ? kj : qi;
        dst[((size_t)rel * NSTMT + n) * 3 + hh] = s;
    }
}

__global__ void edge_logits3(const int* __restrict__ src, const int* __restrict__ dst,
                             const int* __restrict__ et,
                             const float* __restrict__ qi, const float* __restrict__ kj,
                             float* __restrict__ logits)
{
    int e = blockIdx.x * 256 + threadIdx.x;
    if (e >= EST) return;
    int r = et[e], s = src[e], d = dst[e];
    #pragma unroll
    for (int hh = 0; hh < 3; ++hh) {
        float x = qi[((size_t)r * NSTMT + d) * 3 + hh] + kj[((size_t)r * NSTMT + s) * 3 + hh];
        logits[e * 3 + hh] = x > 0 ? x : 0.2f * x;
    }
}

// ---------------- CSR build ----------------
__global__ void count_deg(const int* __restrict__ dst, int* __restrict__ deg)
{
    int e = blockIdx.x * 256 + threadIdx.x;
    if (e < EST) atomicAdd(&deg[dst[e]], 1);
}

__global__ void scan_deg(const int* __restrict__ deg, int* __restrict__ offa)
{
    __shared__ int ts[1024];
    int t = threadIdx.x;
    int base = t * 8;
    int loc[8]; int s = 0;
    #pragma unroll
    for (int i = 0; i < 8; ++i) { loc[i] = s; s += deg[base + i]; }
    ts[t] = s;
    __syncthreads();
    for (int o = 1; o < 1024; o <<= 1) {
        int v = (t >= o) ? ts[t - o] : 0;
        __syncthreads();
        ts[t] += v;
        __syncthreads();
    }
    int prev = (t == 0) ? 0 : ts[t - 1];
    #pragma unroll
    for (int i = 0; i < 8; ++i) offa[base + i] = prev + loc[i];
    if (t == 1023) offa[8192] = ts[1023];
}

__global__ void scatter_csr(const int* __restrict__ dst, const int* __restrict__ offa,
                            int* __restrict__ cnt, int* __restrict__ csr)
{
    int e = blockIdx.x * 256 + threadIdx.x;
    if (e < EST) {
        int d = dst[e];
        int pos = offa[d] + atomicAdd(&cnt[d], 1);
        csr[pos] = e;
    }
}

// ---------------- RGAT0 aggregate ----------------
__global__ __launch_bounds__(256) void rgat_agg3(
    const float* __restrict__ h0, const float* __restrict__ h1,
    const int* __restrict__ offa, const int* __restrict__ csr,
    const int* __restrict__ src, const int* __restrict__ et,
    const float* __restrict__ logits, const float* __restrict__ bias,
    float* __restrict__ out)
{
    int n = blockIdx.x, t = threadIdx.x;
    int o0 = offa[n], deg = offa[n + 1] - o0;
    __shared__ float m[3], sden[3];
    __shared__ float al[64][3];
    __shared__ int esrc[64], erel[64];
    if (t < 3) {
        float mm = -1e30f;
        for (int i = 0; i < deg; ++i) mm = fmaxf(mm, logits[csr[o0 + i] * 3 + t]);
        float ss = 0.f;
        for (int i = 0; i < deg; ++i) ss += expf(logits[csr[o0 + i] * 3 + t] - mm);
        m[t] = mm; sden[t] = fmaxf(ss, 1e-16f);
    }
    __syncthreads();
    float acc0 = 0.f, acc1 = 0.f;
    for (int c0 = 0; c0 < deg; c0 += 64) {
        int cn = min(64, deg - c0);
        if (t < cn) { int e = csr[o0 + c0 + t]; esrc[t] = src[e]; erel[t] = et[e]; }
        if (t < cn * 3) {
            int ee = t / 3, hh = t % 3;
            int e = csr[o0 + c0 + ee];
            al[ee][hh] = expf(logits[e * 3 + hh] - m[hh]) / sden[hh];
        }
        __syncthreads();
        for (int i = 0; i < cn; ++i) {
            const float* hb = (erel[i] ? h1 : h0) + (size_t)esrc[i] * HO3;
            acc0 += al[i][t >> 7] * hb[t];
            if (t < 128) acc1 += al[i][(t + 256) >> 7] * hb[t + 256];
        }
        __syncthreads();
    }
    out[(size_t)n * HO3 + t] = tanhf(acc0 + bias[t]);
    if (t < 128) out[(size_t)n * HO3 + t + 256] = tanhf(acc1 + bias[t + 256]);
}

// ---------------- RGAT1 qi/kj ----------------
__global__ __launch_bounds__(128) void rgat_qk1(
    const float* __restrict__ h0, const float* __restrict__ h1,
    const float* __restrict__ q, const float* __restrict__ k,
    float* __restrict__ qi, float* __restrict__ kj)
{
    int n = blockIdx.x, t = threadIdx.x;
    float v0 = h0[(size_t)n * 128 + t], v1 = h1[(size_t)n * 128 + t];
    float p0 = v0 * q[t], p1 = v0 * k[t], p2 = v1 * q[t], p3 = v1 * k[t];
    __shared__ float red[2][4];
    for (int o = 32; o > 0; o >>= 1) {
        p0 += __shfl_down(p0, o, 64); p1 += __shfl_down(p1, o, 64);
        p2 += __shfl_down(p2, o, 64); p3 += __shfl_down(p3, o, 64);
    }
    if ((t & 63) == 0) { int w = t >> 6; red[w][0] = p0; red[w][1] = p1; red[w][2] = p2; red[w][3] = p3; }
    __syncthreads();
    if (t < 4) {
        float s = red[0][t] + red[1][t];
        if (t == 0) qi[n] = s;
        else if (t == 1) kj[n] = s;
        else if (t == 2) qi[NSTMT + n] = s;
        else kj[NSTMT + n] = s;
    }
}

__global__ void edge_logits1(const int* __restrict__ src, const int* __restrict__ dst,
                             const int* __restrict__ et,
                             const float* __restrict__ qi, const float* __restrict__ kj,
                             float* __restrict__ logits)
{
    int e = blockIdx.x * 256 + threadIdx.x;
    if (e >= EST) return;
    int r = et[e], s = src[e], d = dst[e];
    float x = qi[(size_t)r * NSTMT + d] + kj[(size_t)r * NSTMT + s];
    logits[e] = x > 0 ? x : 0.2f * x;
}

// ---------------- RGAT1 aggregate ----------------
__global__ __launch_bounds__(128) void rgat_agg1(
    const float* __restrict__ h0, const float* __restrict__ h1,
    const int* __restrict__ offa, const int* __restrict__ csr,
    const int* __restrict__ src, const int* __restrict__ et,
    const float* __restrict__ logits, const float* __restrict__ bias,
    float* __restrict__ out)
{
    int n = blockIdx.x, t = threadIdx.x;
    int o0 = offa[n], deg = offa[n + 1] - o0;
    __shared__ float m1, s1;
    __shared__ float al[64];
    __shared__ int esrc[64], erel[64];
    if (t == 0) {
        float mm = -1e30f;
        for (int i = 0; i < deg; ++i) mm = fmaxf(mm, logits[csr[o0 + i]]);
        float ss = 0.f;
        for (int i = 0; i < deg; ++i) ss += expf(logits[csr[o0 + i]] - mm);
        m1 = mm; s1 = fmaxf(ss, 1e-16f);
    }
    __syncthreads();
    float acc = 0.f;
    for (int c0 = 0; c0 < deg; c0 += 64) {
        int cn = min(64, deg - c0);
        if (t < cn) {
            int e = csr[o0 + c0 + t];
            esrc[t] = src[e]; erel[t] = et[e];
            al[t] = expf(logits[e] - m1) / s1;
        }
        __syncthreads();
        for (int i = 0; i < cn; ++i)
            acc += al[i] * ((erel[i] ? h1 : h0)[(size_t)esrc[i] * 128 + t]);
        __syncthreads();
    }
    out[(size_t)n * 128 + t] = tanhf(acc + bias[t]);
}

// ---------------- classifier ----------------
__global__ __launch_bounds__(128) void classifier(
    const float* __restrict__ x, const int* __restrict__ sel,
    const float* __restrict__ w1, const float* __restrict__ b1,
    const float* __restrict__ w2, const float* __restrict__ b2,
    float* __restrict__ out)
{
    __shared__ float row[128];
    __shared__ float t1[128];
    __shared__ float red[2];
    int b = blockIdx.x, t = threadIdx.x;
    int n = sel[b];
    row[t] = x[(size_t)n * 128 + t];
    __syncthreads();
    float acc = b1[t];
    for (int k = 0; k < 128; ++k) acc += row[k] * w1[k * 128 + t];
    t1[t] = fmaxf(acc, 0.f);
    __syncthreads();
    float p = t1[t] * w2[t];
    for (int o = 32; o > 0; o >>= 1) p += __shfl_down(p, o, 64);
    if ((t & 63) == 0) red[t >> 6] = p;
    __syncthreads();
    if (t == 0) {
        float z = red[0] + red[1] + b2[0];
        out[b] = 1.f / (1.f + expf(-z));
    }
}

// ---------------- workspace layout (bytes) ----------------
constexpr size_t OFF_HA     = 0;                       // 201326592
constexpr size_t OFF_BN0    = 201326592;               // 4*768
constexpr size_t OFF_BN1    = OFF_BN0 + 3072;          // 4*256
constexpr size_t OFF_OLDROW = OFF_BN1 + 1024;
constexpr size_t OFF_GATE   = OFF_OLDROW + 753664;
constexpr size_t OFF_PARLOC = OFF_GATE + 753664;
constexpr size_t OFF_HB     = OFF_PARLOC + 753664;     // 48234496 (psum0/psq0 alias)
constexpr size_t OFF_XENC   = OFF_HB + 48234496;       // 4194304 (psum1/psq1 alias)
constexpr size_t OFF_BNSUM  = OFF_XENC + 4194304;
constexpr size_t OFF_BNSQ   = OFF_BNSUM + 1536;
constexpr size_t WS_NEEDED  = OFF_BNSQ + 1536;
// stage-B aliases inside hA (dead after gemm_gather):
constexpr size_t OFF_H0R  = 0;
constexpr size_t OFF_H1R  = 12582912;
constexpr size_t OFF_OUT0 = 25165824;
constexpr size_t OFF_G0   = 37748736;
constexpr size_t OFF_G1   = 41943040;
constexpr size_t OFF_OUT1 = 46137344;
constexpr size_t OFF_QI3  = 50331648;
constexpr size_t OFF_KJ3  = 50528256;
constexpr size_t OFF_LG3  = 50724864;
constexpr size_t OFF_QI1  = 51118080;
constexpr size_t OFF_KJ1  = 51183616;
constexpr size_t OFF_LG1  = 51249152;
constexpr size_t OFF_DEG  = 51380224;
constexpr size_t OFF_OFFA = 51412992;
constexpr size_t OFF_CNT  = 51446016;
constexpr size_t OFF_CSR  = 51478784;

extern "C" void kernel_launch(void* const* d_in, const int* in_sizes, int n_in,
                              void* d_out, int out_size, void* d_ws, size_t ws_size,
                              hipStream_t stream)
{
    if (n_in < 41 || ws_size < WS_NEEDED) return;

    const float* ast_x    = (const float*)d_in[0];
    const int*   ast_src  = (const int*)d_in[1];
    const int*   stmt_src = (const int*)d_in[3];
    const int*   stmt_dst = (const int*)d_in[4];
    const int*   stmt_et  = (const int*)d_in[5];
    const int*   sel      = (const int*)d_in[6];
    const float* gat0_W    = (const float*)d_in[7];
    const float* gat0_asrc = (const float*)d_in[8];
    const float* gat0_adst = (const float*)d_in[9];
    const float* gat0_b    = (const float*)d_in[10];
    const float* bn0_g     = (const float*)d_in[11];
    const float* bn0_b     = (const float*)d_in[12];
    const float* pool0_w   = (const float*)d_in[13];
    const float* gat1_W    = (const float*)d_in[14];
    const float* gat1_asrc = (const float*)d_in[15];
    const float* gat1_adst = (const float*)d_in[16];
    const float* gat1_b    = (const float*)d_in[17];
    const float* bn1_g     = (const float*)d_in[18];
    const float* bn1_b     = (const float*)d_in[19];
    const float* pool1_w   = (const float*)d_in[20];
    const float* enc_w1    = (const float*)d_in[21];
    const float* enc_b1    = (const float*)d_in[22];
    const float* enc_w2    = (const float*)d_in[23];
    const float* enc_b2    = (const float*)d_in[24];
    const float* rgat0_W   = (const float*)d_in[25];
    const float* rgat0_q   = (const float*)d_in[26];
    const float* rgat0_k   = (const float*)d_in[27];
    const float* rgat0_b   = (const float*)d_in[28];
    const float* bnc0_g    = (const float*)d_in[29];
    const float* bnc0_b    = (const float*)d_in[30];
    const float* rgat1_W   = (const float*)d_in[31];
    const float* rgat1_q   = (const float*)d_in[32];
    const float* rgat1_k   = (const float*)d_in[33];
    const float* rgat1_b   = (const float*)d_in[34];
    const float* bnc1_g    = (const float*)d_in[35];
    const float* bnc1_b    = (const float*)d_in[36];
    const float* clf_w1    = (const float*)d_in[37];
    const float* clf_b1    = (const float*)d_in[38];
    const float* clf_w2    = (const float*)d_in[39];
    const float* clf_b2    = (const float*)d_in[40];

    char* ws = (char*)d_ws;
    float* hA     = (float*)(ws + OFF_HA);
    float* ga0    = (float*)(ws + OFF_BN0);
    float* be0    = ga0 + 192;
    float* gw0    = be0 + 192;
    float* bw0    = gw0 + 192;
    float* ga1    = (float*)(ws + OFF_BN1);
    float* be1    = ga1 + 64;
    float* gw1    = be1 + 64;
    float* bw1    = gw1 + 64;
    int*   oldrow = (int*)(ws + OFF_OLDROW);
    float* gate23 = (float*)(ws + OFF_GATE);
    int*   parloc = (int*)(ws + OFF_PARLOC);
    float* hB     = (float*)(ws + OFF_HB);
    float* psum0  = (float*)(ws + OFF_HB);           // [4096][192] alias
    float* psq0   = psum0 + 192 * 4096;
    float* xenc   = (float*)(ws + OFF_XENC);
    float* psum1  = (float*)(ws + OFF_XENC);         // [8192][64] alias
    float* psq1   = psum1 + 64 * 8192;
    float* bnsum  = (float*)(ws + OFF_BNSUM);
    float* bnsq   = (float*)(ws + OFF_BNSQ);

    float* h0r  = (float*)(ws + OFF_H0R);
    float* h1r  = (float*)(ws + OFF_H1R);
    float* out0 = (float*)(ws + OFF_OUT0);
    float* g0   = (float*)(ws + OFF_G0);
    float* g1   = (float*)(ws + OFF_G1);
    float* out1 = (float*)(ws + OFF_OUT1);
    float* qi3  = (float*)(ws + OFF_QI3);
    float* kj3  = (float*)(ws + OFF_KJ3);
    float* lg3  = (float*)(ws + OFF_LG3);
    float* qi1  = (float*)(ws + OFF_QI1);
    float* kj1  = (float*)(ws + OFF_KJ1);
    float* lg1  = (float*)(ws + OFF_LG1);
    int*   deg  = (int*)(ws + OFF_DEG);
    int*   offa = (int*)(ws + OFF_OFFA);
    int*   cnt  = (int*)(ws + OFF_CNT);
    int*   csr  = (int*)(ws + OFF_CSR);

    // ---- Stage A ----
    fused_gat0<<<4096, 192, 0, stream>>>(ast_x, gat0_W, ast_src, gat0_asrc, gat0_adst,
                                         gat0_b, hA, psum0, psq0);
    bn_finalize<<<192, 256, 0, stream>>>(psum0, psq0, 4096, 192, (float)N0,
                                         bn0_g, bn0_b, pool0_w, ga0, be0, gw0, bw0);
    score_topk0<<<G, 256, 0, stream>>>(hA, ast_src, gw0, bw0, pool0_w,
                                       oldrow, gate23, parloc);
    gemm_gather<<<N1 / 64, 256, 0, stream>>>(hA, gat1_W, hB, oldrow, gate23, ga0, be0);
    gat1_att_bn<<<G, 64, 0, stream>>>(hB, parloc, gat1_asrc, gat1_adst, gat1_b,
                                      psum1, psq1);
    bn_finalize<<<64, 256, 0, stream>>>(psum1, psq1, 8192, 64, (float)N1,
                                        bn1_g, bn1_b, pool1_w, ga1, be1, gw1, bw1);
    pool1_mlp<<<G, 128, 0, stream>>>(hB, gw1, bw1, pool1_w, ga1, be1,
                                     enc_w1, enc_b1, enc_w2, enc_b2, xenc);

    // ---- Stage B ----
    gemm_nn<<<dim3(NSTMT / 64, HO3 / 64), 256, 0, stream>>>(xenc, rgat0_W, h0r, NSTMT, HO3, ENC);
    gemm_nn<<<dim3(NSTMT / 64, HO3 / 64), 256, 0, stream>>>(xenc, rgat0_W + (size_t)ENC * HO3, h1r, NSTMT, HO3, ENC);
    rgat_qk3<<<NSTMT, 256, 0, stream>>>(h0r, h1r, rgat0_q, rgat0_k, qi3, kj3);
    edge_logits3<<<EST / 256, 256, 0, stream>>>(stmt_src, stmt_dst, stmt_et, qi3, kj3, lg3);
    hipMemsetAsync(deg, 0, 32768, stream);
    hipMemsetAsync(cnt, 0, 32768, stream);
    count_deg<<<EST / 256, 256, 0, stream>>>(stmt_dst, deg);
    scan_deg<<<1, 1024, 0, stream>>>(deg, offa);
    scatter_csr<<<EST / 256, 256, 0, stream>>>(stmt_dst, offa, cnt, csr);
    rgat_agg3<<<NSTMT, 256, 0, stream>>>(h0r, h1r, offa, csr, stmt_src, stmt_et, lg3, rgat0_b, out0);
    hipMemsetAsync(bnsum, 0, 3072, stream);
    bn_stats<<<256, HO3, 0, stream>>>(out0, NSTMT, bnsum, bnsq);
    bn_apply<<<256, HO3, 0, stream>>>(out0, NSTMT, bnsum, bnsq, bnc0_g, bnc0_b);
    gemm_nn<<<dim3(NSTMT / 64, HOUT / 64), 256, 0, stream>>>(out0, rgat1_W, g0, NSTMT, HOUT, HO3);
    gemm_nn<<<dim3(NSTMT / 64, HOUT / 64), 256, 0, stream>>>(out0, rgat1_W + (size_t)HO3 * HOUT, g1, NSTMT, HOUT, HO3);
    rgat_qk1<<<NSTMT, 128, 0, stream>>>(g0, g1, rgat1_q, rgat1_k, qi1, kj1);
    edge_logits1<<<EST / 256, 256, 0, stream>>>(stmt_src, stmt_dst, stmt_et, qi1, kj1, lg1);
    rgat_agg1<<<NSTMT, 128, 0, stream>>>(g0, g1, offa, csr, stmt_src, stmt_et, lg1, rgat1_b, out1);
    hipMemsetAsync(bnsum, 0, 3072, stream);
    bn_stats<<<256, HOUT, 0, stream>>>(out1, NSTMT, bnsum, bnsq);
    bn_apply<<<256, HOUT, 0, stream>>>(out1, NSTMT, bnsum, bnsq, bnc1_g, bnc1_b);
    classifier<<<NSEL, 128, 0, stream>>>(out1, sel, clf_w1, clf_b1, clf_w2, clf_b2, (float*)d_out);
}